// Round 1
// baseline (1987.564 us; speedup 1.0000x reference)
//
#include <hip/hip_runtime.h>

// GraphSAGE 2-layer: h = relu(mean_agg(x,ei1)@W1l + x@W1r + b1)
//                    out = softmax(mean_agg(h,ei2)@W2l + h@W2r + b2)
// N=100000, E=1600000, IN=HID=128, OUT=64, all f32 (edge_index int32 or int64).

#define FEAT 128
#define OUTF 64

// ---------------------------------------------------------------------------
// Detect whether edge_index arrays are int64 (8B) or int32 (4B).
// Indices are in [0, 100000), so if int64 every odd 32-bit word (high half)
// is zero. If int32, odd words are random indices — P(all 256 zero) ~ 0.
// flag != 0  =>  int32.
__global__ void detect_idx_kernel(const unsigned* __restrict__ ei, unsigned* __restrict__ flag) {
    unsigned v = ei[2 * threadIdx.x + 1];
    if (v != 0u) atomicOr(flag, 1u);
}

// ---------------------------------------------------------------------------
// Scatter-accumulate: for each edge e, agg[dst[e]] += feat[src[e]], cnt[dst[e]] += 1.
// One thread per (edge, feature). agg/cnt must be pre-zeroed.
__global__ __launch_bounds__(256) void scatter_kernel(
    const void* __restrict__ ei_raw, const float* __restrict__ feat,
    float* __restrict__ agg, float* __restrict__ cnt,
    const unsigned* __restrict__ flag, int nedge) {
    const bool is32 = (*flag != 0u);
    const int total = nedge * FEAT;   // 204.8M < 2^31
    for (int i = blockIdx.x * blockDim.x + threadIdx.x; i < total;
         i += gridDim.x * blockDim.x) {
        int e = i >> 7;
        int f = i & (FEAT - 1);
        int src, dst;
        if (is32) {
            const int* ei = (const int*)ei_raw;
            src = ei[e];
            dst = ei[nedge + e];
        } else {
            const long long* ei = (const long long*)ei_raw;
            src = (int)ei[e];
            dst = (int)ei[nedge + e];
        }
        float v = feat[src * FEAT + f];
        atomicAdd(&agg[dst * FEAT + f], v);
        if (f == 0) atomicAdd(&cnt[dst], 1.0f);
    }
}

// ---------------------------------------------------------------------------
// Layer 1: h[node] = relu( (agg[node]/max(cnt,1)) @ Wl + x[node] @ Wr + b )
// Both 128x128 W matrices staged in LDS (128 KiB). 8 nodes per block-iteration;
// thread (slot=tid>>5, c4=(tid&31)*4) computes 4 output cols of one node.
__global__ __launch_bounds__(256, 1) void layer1_kernel(
    const float* __restrict__ x, const float* __restrict__ agg,
    const float* __restrict__ cnt, const float* __restrict__ Wl,
    const float* __restrict__ Wr, const float* __restrict__ b,
    float* __restrict__ h, int n) {
    __shared__ float sWl[FEAT * FEAT];
    __shared__ float sWr[FEAT * FEAT];
    __shared__ float rows[8][2][FEAT];   // [slot][0=mean-agg,1=x][k]
    const int tid = threadIdx.x;

    for (int i = tid * 4; i < FEAT * FEAT; i += 256 * 4) {
        *(float4*)&sWl[i] = *(const float4*)&Wl[i];
        *(float4*)&sWr[i] = *(const float4*)&Wr[i];
    }

    const int slot = tid >> 5;          // 0..7
    const int c4 = (tid & 31) * 4;      // output col base

    for (int base = blockIdx.x * 8; base < n; base += gridDim.x * 8) {
        __syncthreads();                // W ready (first iter) / rows no longer in use
        // Stage 8 nodes x 2 rows x 128 floats = 512 float4; 2 per thread.
        for (int j = tid; j < 512; j += 256) {
            int ns = j >> 6;            // node slot 0..7
            int r = (j >> 5) & 1;       // 0 = agg, 1 = x
            int kk = (j & 31) * 4;
            int node = base + ns;
            float4 val = make_float4(0.f, 0.f, 0.f, 0.f);
            if (node < n) {
                if (r == 0) {
                    float inv = 1.0f / fmaxf(cnt[node], 1.0f);
                    float4 a = *(const float4*)&agg[node * FEAT + kk];
                    val = make_float4(a.x * inv, a.y * inv, a.z * inv, a.w * inv);
                } else {
                    val = *(const float4*)&x[node * FEAT + kk];
                }
            }
            *(float4*)&rows[ns][r][kk] = val;
        }
        __syncthreads();

        int node = base + slot;
        float4 acc = make_float4(0.f, 0.f, 0.f, 0.f);
        #pragma unroll 8
        for (int k = 0; k < FEAT; ++k) {
            float a = rows[slot][0][k];
            float xv = rows[slot][1][k];
            float4 wl = *(const float4*)&sWl[k * FEAT + c4];
            float4 wr = *(const float4*)&sWr[k * FEAT + c4];
            acc.x += a * wl.x + xv * wr.x;
            acc.y += a * wl.y + xv * wr.y;
            acc.z += a * wl.z + xv * wr.z;
            acc.w += a * wl.w + xv * wr.w;
        }
        if (node < n) {
            float4 bb = *(const float4*)&b[c4];
            float4 o;
            o.x = fmaxf(acc.x + bb.x, 0.f);
            o.y = fmaxf(acc.y + bb.y, 0.f);
            o.z = fmaxf(acc.z + bb.z, 0.f);
            o.w = fmaxf(acc.w + bb.w, 0.f);
            *(float4*)&h[node * FEAT + c4] = o;
        }
    }
}

// ---------------------------------------------------------------------------
// Layer 2: out[node] = softmax( (agg/max(cnt,1)) @ Wl + h @ Wr + b )  (64 cols)
// W2 matrices (128x64 each) staged in LDS (64 KiB). 4 nodes per iteration;
// one 64-lane wave per node, one output col per lane; softmax via shfl_xor.
__global__ __launch_bounds__(256, 2) void layer2_kernel(
    const float* __restrict__ h, const float* __restrict__ agg,
    const float* __restrict__ cnt, const float* __restrict__ Wl,
    const float* __restrict__ Wr, const float* __restrict__ b,
    float* __restrict__ out, int n) {
    __shared__ float sWl[FEAT * OUTF];
    __shared__ float sWr[FEAT * OUTF];
    __shared__ float rows[4][2][FEAT];
    const int tid = threadIdx.x;

    for (int i = tid * 4; i < FEAT * OUTF; i += 256 * 4) {
        *(float4*)&sWl[i] = *(const float4*)&Wl[i];
        *(float4*)&sWr[i] = *(const float4*)&Wr[i];
    }

    const int slot = tid >> 6;          // wave id 0..3 (one node per wave)
    const int c = tid & 63;             // output col

    for (int base = blockIdx.x * 4; base < n; base += gridDim.x * 4) {
        __syncthreads();
        // 4 nodes x 2 rows x 128 floats = 256 float4; 1 per thread.
        {
            int j = tid;
            int ns = j >> 6;
            int r = (j >> 5) & 1;
            int kk = (j & 31) * 4;
            int node = base + ns;
            float4 val = make_float4(0.f, 0.f, 0.f, 0.f);
            if (node < n) {
                if (r == 0) {
                    float inv = 1.0f / fmaxf(cnt[node], 1.0f);
                    float4 a = *(const float4*)&agg[node * FEAT + kk];
                    val = make_float4(a.x * inv, a.y * inv, a.z * inv, a.w * inv);
                } else {
                    val = *(const float4*)&h[node * FEAT + kk];
                }
            }
            *(float4*)&rows[ns][r][kk] = val;
        }
        __syncthreads();

        int node = base + slot;
        float acc = 0.f;
        #pragma unroll 8
        for (int k = 0; k < FEAT; ++k) {
            acc += rows[slot][0][k] * sWl[k * OUTF + c] +
                   rows[slot][1][k] * sWr[k * OUTF + c];
        }
        acc += b[c];

        // softmax across the 64 lanes of this wave
        float m = acc;
        for (int off = 32; off > 0; off >>= 1)
            m = fmaxf(m, __shfl_xor(m, off, 64));
        float ev = __expf(acc - m);
        float s = ev;
        for (int off = 32; off > 0; off >>= 1)
            s += __shfl_xor(s, off, 64);
        if (node < n) out[node * OUTF + c] = ev / s;
    }
}

// ---------------------------------------------------------------------------
extern "C" void kernel_launch(void* const* d_in, const int* in_sizes, int n_in,
                              void* d_out, int out_size, void* d_ws, size_t ws_size,
                              hipStream_t stream) {
    const float* x   = (const float*)d_in[0];
    const float* W1l = (const float*)d_in[1];
    const float* W1r = (const float*)d_in[2];
    const float* b1  = (const float*)d_in[3];
    const float* W2l = (const float*)d_in[4];
    const float* W2r = (const float*)d_in[5];
    const float* b2  = (const float*)d_in[6];
    const void*  ei1 = d_in[7];
    const void*  ei2 = d_in[8];
    float* out = (float*)d_out;

    const int n  = in_sizes[0] / FEAT;   // 100000
    const int e1 = in_sizes[7] / 2;      // 1600000
    const int e2 = in_sizes[8] / 2;

    // Workspace layout: [flag:256B][agg: n*128*4][cnt: n*4 padded][h: n*128*4]
    char* ws = (char*)d_ws;
    const size_t aggBytes = (size_t)n * FEAT * 4;
    const size_t cntBytes = ((size_t)n * 4 + 255) & ~(size_t)255;
    unsigned* flag = (unsigned*)ws;
    float* agg = (float*)(ws + 256);
    float* cnt = (float*)(ws + 256 + aggBytes);
    float* h   = (float*)(ws + 256 + aggBytes + cntBytes);
    if (ws_size < 256 + aggBytes + cntBytes + aggBytes) return;  // need ~103 MB

    const int scatterGrid = 16384;       // grid-stride over E*128 threads

    hipMemsetAsync(flag, 0, 4, stream);
    detect_idx_kernel<<<1, 256, 0, stream>>>((const unsigned*)ei1, flag);

    // ---- layer 1 ----
    hipMemsetAsync(agg, 0, aggBytes, stream);
    hipMemsetAsync(cnt, 0, (size_t)n * 4, stream);
    scatter_kernel<<<scatterGrid, 256, 0, stream>>>(ei1, x, agg, cnt, flag, e1);
    layer1_kernel<<<256, 256, 0, stream>>>(x, agg, cnt, W1l, W1r, b1, h, n);

    // ---- layer 2 ----
    hipMemsetAsync(agg, 0, aggBytes, stream);
    hipMemsetAsync(cnt, 0, (size_t)n * 4, stream);
    scatter_kernel<<<scatterGrid, 256, 0, stream>>>(ei2, h, agg, cnt, flag, e2);
    layer2_kernel<<<512, 256, 0, stream>>>(h, agg, cnt, W2l, W2r, b2, out, n);
}

// Round 2
// 1845.501 us; speedup vs baseline: 1.0770x; 1.0770x over previous
//
#include <hip/hip_runtime.h>

// GraphSAGE 2-layer, CSR-gather formulation (no scatter atomics on features):
//   per layer: hist(dst) -> exclusive scan -> fill CSR -> fused gather+mean+GEMM
// N=100000, E=1600000, IN=HID=128, OUT=64, f32; edge_index int32 or int64.

#define FEAT 128
#define OUTF 64

// ---------------------------------------------------------------------------
// Detect int64 (8B) vs int32 (4B) edge indices. Indices < 100000, so int64 =>
// every odd 32-bit word is 0. flag != 0 => int32.
__global__ void detect_idx_kernel(const unsigned* __restrict__ ei, unsigned* __restrict__ flag) {
    unsigned v = ei[2 * threadIdx.x + 1];
    if (v != 0u) atomicOr(flag, 1u);
}

// ---------------------------------------------------------------------------
__global__ __launch_bounds__(256) void hist_kernel(
    const void* __restrict__ ei_raw, unsigned* __restrict__ deg,
    const unsigned* __restrict__ flag, int nedge) {
    const bool is32 = (*flag != 0u);
    for (int e = blockIdx.x * blockDim.x + threadIdx.x; e < nedge;
         e += gridDim.x * blockDim.x) {
        int dst = is32 ? ((const int*)ei_raw)[nedge + e]
                       : (int)((const long long*)ei_raw)[nedge + e];
        atomicAdd(&deg[dst], 1u);
    }
}

// ---------------------------------------------------------------------------
// Single-block exclusive scan of deg[0..n) -> row_ptr[0..n]. 1024 threads,
// wave-shfl scan + serial combine of 16 wave sums.
__global__ __launch_bounds__(1024) void scan_kernel(
    const unsigned* __restrict__ deg, unsigned* __restrict__ row_ptr, int n) {
    __shared__ unsigned wsum[16], woff[16], s_total;
    const int tid = threadIdx.x;
    const int lane = tid & 63;
    unsigned carry = 0;
    for (int base = 0; base < n; base += 1024) {
        int i = base + tid;
        unsigned v = (i < n) ? deg[i] : 0u;
        unsigned incl = v;
        #pragma unroll
        for (int off = 1; off < 64; off <<= 1) {
            unsigned t = __shfl_up(incl, off, 64);
            if (lane >= off) incl += t;
        }
        if (lane == 63) wsum[tid >> 6] = incl;
        __syncthreads();
        if (tid == 0) {
            unsigned s = 0;
            #pragma unroll
            for (int w = 0; w < 16; ++w) { unsigned t = wsum[w]; woff[w] = s; s += t; }
            s_total = s;
        }
        __syncthreads();
        unsigned excl = carry + woff[tid >> 6] + incl - v;
        if (i < n) row_ptr[i] = excl;
        carry += s_total;
        __syncthreads();   // protect wsum/woff/s_total before next iteration
    }
    if (tid == 0) row_ptr[n] = carry;
}

// ---------------------------------------------------------------------------
__global__ __launch_bounds__(256) void fill_kernel(
    const void* __restrict__ ei_raw, const unsigned* __restrict__ row_ptr,
    unsigned* __restrict__ fill, int* __restrict__ esrc,
    const unsigned* __restrict__ flag, int nedge) {
    const bool is32 = (*flag != 0u);
    for (int e = blockIdx.x * blockDim.x + threadIdx.x; e < nedge;
         e += gridDim.x * blockDim.x) {
        int src, dst;
        if (is32) {
            const int* ei = (const int*)ei_raw;
            src = ei[e]; dst = ei[nedge + e];
        } else {
            const long long* ei = (const long long*)ei_raw;
            src = (int)ei[e]; dst = (int)ei[nedge + e];
        }
        unsigned pos = row_ptr[dst] + atomicAdd(&fill[dst], 1u);
        esrc[pos] = src;
    }
}

// ---------------------------------------------------------------------------
// Layer 1 fused: h[i] = relu(mean_{j in N(i)} x[j] @ Wl + x[i] @ Wr + b)
// 16 nodes per block-iteration; slot = tid>>5 owns 2 nodes; lanes gather float4.
__global__ __launch_bounds__(256, 1) void layer1_kernel(
    const float* __restrict__ x, const unsigned* __restrict__ row_ptr,
    const int* __restrict__ esrc, const float* __restrict__ Wl,
    const float* __restrict__ Wr, const float* __restrict__ b,
    float* __restrict__ h, int n) {
    __shared__ float sWl[FEAT * FEAT];
    __shared__ float sWr[FEAT * FEAT];
    __shared__ float rows[16][2][FEAT];   // [node-slot][0=mean,1=self][k]
    const int tid = threadIdx.x;

    for (int i = tid * 4; i < FEAT * FEAT; i += 256 * 4) {
        *(float4*)&sWl[i] = *(const float4*)&Wl[i];
        *(float4*)&sWr[i] = *(const float4*)&Wr[i];
    }

    const int slot = tid >> 5;          // 0..7, owns nodes slot*2, slot*2+1
    const int l4 = (tid & 31) * 4;      // feature / output-col base

    for (int base = blockIdx.x * 16; base < n; base += gridDim.x * 16) {
        __syncthreads();
        // ---- gather + mean + self-row staging ----
        #pragma unroll
        for (int i = 0; i < 2; ++i) {
            int ns = slot * 2 + i;
            int node = base + ns;
            float4 acc = make_float4(0.f, 0.f, 0.f, 0.f);
            float4 self = make_float4(0.f, 0.f, 0.f, 0.f);
            if (node < n) {
                unsigned rs = row_ptr[node], re = row_ptr[node + 1];
                for (unsigned j = rs; j < re; ++j) {
                    int s = esrc[j];
                    float4 v = *(const float4*)&x[(size_t)s * FEAT + l4];
                    acc.x += v.x; acc.y += v.y; acc.z += v.z; acc.w += v.w;
                }
                float inv = (re > rs) ? 1.0f / (float)(re - rs) : 0.0f;
                acc.x *= inv; acc.y *= inv; acc.z *= inv; acc.w *= inv;
                self = *(const float4*)&x[(size_t)node * FEAT + l4];
            }
            *(float4*)&rows[ns][0][l4] = acc;
            *(float4*)&rows[ns][1][l4] = self;
        }
        __syncthreads();

        // ---- GEMM: 2 nodes x 4 cols per thread, k in chunks of 4 ----
        const int n0 = slot * 2, n1 = n0 + 1;
        float4 acc0 = make_float4(0.f, 0.f, 0.f, 0.f);
        float4 acc1 = make_float4(0.f, 0.f, 0.f, 0.f);
        for (int kk = 0; kk < FEAT; kk += 4) {
            float a0[4], x0[4], a1[4], x1[4];
            *(float4*)a0 = *(const float4*)&rows[n0][0][kk];
            *(float4*)x0 = *(const float4*)&rows[n0][1][kk];
            *(float4*)a1 = *(const float4*)&rows[n1][0][kk];
            *(float4*)x1 = *(const float4*)&rows[n1][1][kk];
            #pragma unroll
            for (int j = 0; j < 4; ++j) {
                float4 wl = *(const float4*)&sWl[(kk + j) * FEAT + l4];
                float4 wr = *(const float4*)&sWr[(kk + j) * FEAT + l4];
                acc0.x += a0[j] * wl.x + x0[j] * wr.x;
                acc0.y += a0[j] * wl.y + x0[j] * wr.y;
                acc0.z += a0[j] * wl.z + x0[j] * wr.z;
                acc0.w += a0[j] * wl.w + x0[j] * wr.w;
                acc1.x += a1[j] * wl.x + x1[j] * wr.x;
                acc1.y += a1[j] * wl.y + x1[j] * wr.y;
                acc1.z += a1[j] * wl.z + x1[j] * wr.z;
                acc1.w += a1[j] * wl.w + x1[j] * wr.w;
            }
        }
        float4 bb = *(const float4*)&b[l4];
        int node0 = base + n0, node1 = base + n1;
        if (node0 < n) {
            float4 o;
            o.x = fmaxf(acc0.x + bb.x, 0.f); o.y = fmaxf(acc0.y + bb.y, 0.f);
            o.z = fmaxf(acc0.z + bb.z, 0.f); o.w = fmaxf(acc0.w + bb.w, 0.f);
            *(float4*)&h[(size_t)node0 * FEAT + l4] = o;
        }
        if (node1 < n) {
            float4 o;
            o.x = fmaxf(acc1.x + bb.x, 0.f); o.y = fmaxf(acc1.y + bb.y, 0.f);
            o.z = fmaxf(acc1.z + bb.z, 0.f); o.w = fmaxf(acc1.w + bb.w, 0.f);
            *(float4*)&h[(size_t)node1 * FEAT + l4] = o;
        }
    }
}

// ---------------------------------------------------------------------------
// Layer 2 fused: out[i] = softmax(mean_{j} h[j] @ Wl + h[i] @ Wr + b)  (64 cols)
// 16 nodes per block-iteration; wave slot = tid>>6 owns 4 nodes; softmax via shfl.
__global__ __launch_bounds__(256, 2) void layer2_kernel(
    const float* __restrict__ hbuf, const unsigned* __restrict__ row_ptr,
    const int* __restrict__ esrc, const float* __restrict__ Wl,
    const float* __restrict__ Wr, const float* __restrict__ b,
    float* __restrict__ out, int n) {
    __shared__ float sWl[FEAT * OUTF];
    __shared__ float sWr[FEAT * OUTF];
    __shared__ float rows[16][2][FEAT];
    const int tid = threadIdx.x;

    for (int i = tid * 4; i < FEAT * OUTF; i += 256 * 4) {
        *(float4*)&sWl[i] = *(const float4*)&Wl[i];
        *(float4*)&sWr[i] = *(const float4*)&Wr[i];
    }

    const int slot = tid >> 6;          // wave 0..3, owns 4 nodes
    const int lane = tid & 63;          // output col / gather lane
    const int l2 = lane * 2;

    for (int base = blockIdx.x * 16; base < n; base += gridDim.x * 16) {
        __syncthreads();
        // ---- gather + mean + self staging (float2 per lane) ----
        #pragma unroll
        for (int i = 0; i < 4; ++i) {
            int ns = slot * 4 + i;
            int node = base + ns;
            float2 acc = make_float2(0.f, 0.f);
            float2 self = make_float2(0.f, 0.f);
            if (node < n) {
                unsigned rs = row_ptr[node], re = row_ptr[node + 1];
                for (unsigned j = rs; j < re; ++j) {
                    int s = esrc[j];
                    float2 v = *(const float2*)&hbuf[(size_t)s * FEAT + l2];
                    acc.x += v.x; acc.y += v.y;
                }
                float inv = (re > rs) ? 1.0f / (float)(re - rs) : 0.0f;
                acc.x *= inv; acc.y *= inv;
                self = *(const float2*)&hbuf[(size_t)node * FEAT + l2];
            }
            *(float2*)&rows[ns][0][l2] = acc;
            *(float2*)&rows[ns][1][l2] = self;
        }
        __syncthreads();

        // ---- GEMM: 4 nodes x 1 col per thread, k in chunks of 4 ----
        float acc[4] = {0.f, 0.f, 0.f, 0.f};
        for (int kk = 0; kk < FEAT; kk += 4) {
            float wlr[4], wrr[4];
            #pragma unroll
            for (int j = 0; j < 4; ++j) {
                wlr[j] = sWl[(kk + j) * OUTF + lane];
                wrr[j] = sWr[(kk + j) * OUTF + lane];
            }
            #pragma unroll
            for (int i = 0; i < 4; ++i) {
                float a[4], xv[4];
                *(float4*)a  = *(const float4*)&rows[slot * 4 + i][0][kk];
                *(float4*)xv = *(const float4*)&rows[slot * 4 + i][1][kk];
                acc[i] += a[0] * wlr[0] + xv[0] * wrr[0]
                        + a[1] * wlr[1] + xv[1] * wrr[1]
                        + a[2] * wlr[2] + xv[2] * wrr[2]
                        + a[3] * wlr[3] + xv[3] * wrr[3];
            }
        }
        float bc = b[lane];
        #pragma unroll
        for (int i = 0; i < 4; ++i) {
            int node = base + slot * 4 + i;
            float v = acc[i] + bc;
            float m = v;
            for (int off = 32; off > 0; off >>= 1)
                m = fmaxf(m, __shfl_xor(m, off, 64));
            float ev = __expf(v - m);
            float s = ev;
            for (int off = 32; off > 0; off >>= 1)
                s += __shfl_xor(s, off, 64);
            if (node < n) out[(size_t)node * OUTF + lane] = ev / s;
        }
    }
}

// ---------------------------------------------------------------------------
extern "C" void kernel_launch(void* const* d_in, const int* in_sizes, int n_in,
                              void* d_out, int out_size, void* d_ws, size_t ws_size,
                              hipStream_t stream) {
    const float* x   = (const float*)d_in[0];
    const float* W1l = (const float*)d_in[1];
    const float* W1r = (const float*)d_in[2];
    const float* b1  = (const float*)d_in[3];
    const float* W2l = (const float*)d_in[4];
    const float* W2r = (const float*)d_in[5];
    const float* b2  = (const float*)d_in[6];
    const void*  ei1 = d_in[7];
    const void*  ei2 = d_in[8];
    float* out = (float*)d_out;

    const int n  = in_sizes[0] / FEAT;   // 100000
    const int e1 = in_sizes[7] / 2;      // 1600000
    const int e2 = in_sizes[8] / 2;

    // Workspace: [flag 256B][h n*128*4][row_ptr (n+1)u32][deg n u32][fill n u32][esrc E int]
    char* ws = (char*)d_ws;
    const size_t hBytes  = (size_t)n * FEAT * 4;
    const size_t rpBytes = (((size_t)(n + 1) * 4) + 255) & ~(size_t)255;
    const size_t dBytes  = (((size_t)n * 4) + 255) & ~(size_t)255;
    const int emax = (e1 > e2) ? e1 : e2;
    unsigned* flag    = (unsigned*)ws;
    float*    h       = (float*)(ws + 256);
    unsigned* row_ptr = (unsigned*)(ws + 256 + hBytes);
    unsigned* deg     = (unsigned*)(ws + 256 + hBytes + rpBytes);
    unsigned* fillb   = (unsigned*)(ws + 256 + hBytes + rpBytes + dBytes);
    int*      esrc    = (int*)(ws + 256 + hBytes + rpBytes + 2 * dBytes);
    if (ws_size < 256 + hBytes + rpBytes + 2 * dBytes + (size_t)emax * 4) return;

    hipMemsetAsync(flag, 0, 4, stream);
    detect_idx_kernel<<<1, 256, 0, stream>>>((const unsigned*)ei1, flag);

    // ---- layer 1: CSR(ei1) + fused gather/GEMM/relu ----
    hipMemsetAsync(deg, 0, (size_t)n * 4, stream);
    hipMemsetAsync(fillb, 0, (size_t)n * 4, stream);
    hist_kernel<<<2048, 256, 0, stream>>>(ei1, deg, flag, e1);
    scan_kernel<<<1, 1024, 0, stream>>>(deg, row_ptr, n);
    fill_kernel<<<2048, 256, 0, stream>>>(ei1, row_ptr, fillb, esrc, flag, e1);
    layer1_kernel<<<256, 256, 0, stream>>>(x, row_ptr, esrc, W1l, W1r, b1, h, n);

    // ---- layer 2: CSR(ei2) + fused gather/GEMM/softmax ----
    hipMemsetAsync(deg, 0, (size_t)n * 4, stream);
    hipMemsetAsync(fillb, 0, (size_t)n * 4, stream);
    hist_kernel<<<2048, 256, 0, stream>>>(ei2, deg, flag, e2);
    scan_kernel<<<1, 1024, 0, stream>>>(deg, row_ptr, n);
    fill_kernel<<<2048, 256, 0, stream>>>(ei2, row_ptr, fillb, esrc, flag, e2);
    layer2_kernel<<<512, 256, 0, stream>>>(h, row_ptr, esrc, W2l, W2r, b2, out, n);
}

// Round 3
// 1211.089 us; speedup vs baseline: 1.6411x; 1.5238x over previous
//
#include <hip/hip_runtime.h>

// GraphSAGE 2-layer, decoupled pipeline per layer:
//   hist -> in-place scan -> fill (CSR, single rp buffer holding row ENDS)
//   gather_mean (high-occupancy, agg stored bf16)
//   gemm (W in LDS, 4x4 per-thread tiles, f32 FMA)
// N=100000, E=1600000, IN=HID=128, OUT=64; edge_index int32 or int64.

#define FEAT 128
#define OUTF 64

__device__ __forceinline__ unsigned f2bf_rne(float f) {
    unsigned u = __float_as_uint(f);
    return (u + 0x7fffu + ((u >> 16) & 1u)) >> 16;
}

// ---------------------------------------------------------------------------
// int64 vs int32 detection: indices < 100000 so int64 => odd 32-bit words all 0.
__global__ void detect_idx_kernel(const unsigned* __restrict__ ei, unsigned* __restrict__ flag) {
    unsigned v = ei[2 * threadIdx.x + 1];
    if (v != 0u) atomicOr(flag, 1u);
}

// ---------------------------------------------------------------------------
__global__ __launch_bounds__(256) void hist_kernel(
    const void* __restrict__ ei_raw, unsigned* __restrict__ rp,
    const unsigned* __restrict__ flag, int nedge) {
    const bool is32 = (*flag != 0u);
    for (int e = blockIdx.x * blockDim.x + threadIdx.x; e < nedge;
         e += gridDim.x * blockDim.x) {
        int dst = is32 ? ((const int*)ei_raw)[nedge + e]
                       : (int)((const long long*)ei_raw)[nedge + e];
        atomicAdd(&rp[dst], 1u);
    }
}

// ---------------------------------------------------------------------------
// In-place exclusive scan of rp[0..n). Single block, 1024 threads.
__global__ __launch_bounds__(1024) void scan_kernel(unsigned* __restrict__ rp, int n) {
    __shared__ unsigned wsum[16], woff[16], s_total;
    const int tid = threadIdx.x;
    const int lane = tid & 63;
    unsigned carry = 0;
    for (int base = 0; base < n; base += 1024) {
        int i = base + tid;
        unsigned v = (i < n) ? rp[i] : 0u;
        unsigned incl = v;
        #pragma unroll
        for (int off = 1; off < 64; off <<= 1) {
            unsigned t = __shfl_up(incl, off, 64);
            if (lane >= off) incl += t;
        }
        if (lane == 63) wsum[tid >> 6] = incl;
        __syncthreads();
        if (tid == 0) {
            unsigned s = 0;
            #pragma unroll
            for (int w = 0; w < 16; ++w) { unsigned t = wsum[w]; woff[w] = s; s += t; }
            s_total = s;
        }
        __syncthreads();
        if (i < n) rp[i] = carry + woff[tid >> 6] + incl - v;
        carry += s_total;
        __syncthreads();   // protect wsum/woff/s_total for next chunk
    }
}

// ---------------------------------------------------------------------------
// Fill CSR. atomicAdd on rp turns row STARTS into row ENDS as a side effect:
// after this kernel, rp[i] = end_i and start_i = (i ? rp[i-1] : 0).
__global__ __launch_bounds__(256) void fill_kernel(
    const void* __restrict__ ei_raw, unsigned* __restrict__ rp,
    int* __restrict__ esrc, const unsigned* __restrict__ flag, int nedge) {
    const bool is32 = (*flag != 0u);
    for (int e = blockIdx.x * blockDim.x + threadIdx.x; e < nedge;
         e += gridDim.x * blockDim.x) {
        int src, dst;
        if (is32) {
            const int* ei = (const int*)ei_raw;
            src = ei[e]; dst = ei[nedge + e];
        } else {
            const long long* ei = (const long long*)ei_raw;
            src = (int)ei[e]; dst = (int)ei[nedge + e];
        }
        unsigned pos = atomicAdd(&rp[dst], 1u);
        esrc[pos] = src;
    }
}

// ---------------------------------------------------------------------------
// Mean-gather: agg[i][:] = mean_{j in N(i)} feat[j][:], stored bf16.
// One wave per node, 64 lanes x float2. No LDS, low VGPR -> max occupancy.
__global__ __launch_bounds__(256) void gather_mean_kernel(
    const float* __restrict__ feat, const unsigned* __restrict__ rp,
    const int* __restrict__ esrc, unsigned* __restrict__ agg /* bf16x2 words */,
    int n) {
    const int wave = threadIdx.x >> 6;
    const int lane = threadIdx.x & 63;
    const int l2 = lane * 2;
    for (int node = blockIdx.x * 4 + wave; node < n; node += gridDim.x * 4) {
        unsigned rs = node ? rp[node - 1] : 0u;
        unsigned re = rp[node];
        float ax = 0.f, ay = 0.f;
        unsigned j = rs;
        for (; j + 4 <= re; j += 4) {
            int s0 = esrc[j], s1 = esrc[j + 1], s2 = esrc[j + 2], s3 = esrc[j + 3];
            float2 v0 = *(const float2*)&feat[(size_t)s0 * FEAT + l2];
            float2 v1 = *(const float2*)&feat[(size_t)s1 * FEAT + l2];
            float2 v2 = *(const float2*)&feat[(size_t)s2 * FEAT + l2];
            float2 v3 = *(const float2*)&feat[(size_t)s3 * FEAT + l2];
            ax += v0.x + v1.x + v2.x + v3.x;
            ay += v0.y + v1.y + v2.y + v3.y;
        }
        for (; j < re; ++j) {
            float2 v = *(const float2*)&feat[(size_t)esrc[j] * FEAT + l2];
            ax += v.x; ay += v.y;
        }
        float inv = (re > rs) ? 1.0f / (float)(re - rs) : 0.0f;
        ax *= inv; ay *= inv;
        agg[(size_t)node * (FEAT / 2) + lane] = f2bf_rne(ax) | (f2bf_rne(ay) << 16);
    }
}

// ---------------------------------------------------------------------------
// GEMM layer1: h = relu(agg@Wl + x@Wr + b). Col-split: block handles 64 of 128
// output cols. 64 nodes/block-iter; thread tile = 4 nodes x 4 cols.
__global__ __launch_bounds__(256, 1) void gemm1_kernel(
    const unsigned* __restrict__ agg, const float* __restrict__ x,
    const float* __restrict__ Wl, const float* __restrict__ Wr,
    const float* __restrict__ b, float* __restrict__ h, int n) {
    __shared__ float sWl[FEAT * 64];
    __shared__ float sWr[FEAT * 64];
    __shared__ float rows[64][2][132];   // padded: node stride 264 % 32 = 8
    const int tid = threadIdx.x;
    const int c0 = (blockIdx.x & 1) * 64;

    for (int i = tid * 4; i < FEAT * 64; i += 256 * 4) {
        int k = i >> 6, cc = i & 63;
        *(float4*)&sWl[i] = *(const float4*)&Wl[k * FEAT + c0 + cc];
        *(float4*)&sWr[i] = *(const float4*)&Wr[k * FEAT + c0 + cc];
    }

    const int ct = tid & 15;     // col group: cols c0 + ct*4
    const int ng = tid >> 4;     // node group: nodes i*16 + ng, i=0..3

    for (int base = (blockIdx.x >> 1) * 64; base < n; base += (gridDim.x >> 1) * 64) {
        __syncthreads();
        // stage 64 nodes x {agg(bf16), x(f32)} x 128 feats
        for (int j = tid; j < 4096; j += 256) {
            int ns = j >> 6;
            int r = (j >> 5) & 1;
            int kk = (j & 31) * 4;
            int node = base + ns;
            float4 v = make_float4(0.f, 0.f, 0.f, 0.f);
            if (node < n) {
                if (r == 0) {
                    uint2 u = *(const uint2*)&agg[(size_t)node * (FEAT / 2) + (kk >> 1)];
                    v.x = __uint_as_float(u.x << 16);
                    v.y = __uint_as_float(u.x & 0xffff0000u);
                    v.z = __uint_as_float(u.y << 16);
                    v.w = __uint_as_float(u.y & 0xffff0000u);
                } else {
                    v = *(const float4*)&x[(size_t)node * FEAT + kk];
                }
            }
            *(float4*)&rows[ns][r][kk] = v;
        }
        __syncthreads();

        float4 acc[4];
        #pragma unroll
        for (int i = 0; i < 4; ++i) acc[i] = make_float4(0.f, 0.f, 0.f, 0.f);
        #pragma unroll 4
        for (int k = 0; k < FEAT; ++k) {
            float4 wl = *(const float4*)&sWl[k * 64 + ct * 4];
            float4 wr = *(const float4*)&sWr[k * 64 + ct * 4];
            #pragma unroll
            for (int i = 0; i < 4; ++i) {
                float a = rows[i * 16 + ng][0][k];
                float s = rows[i * 16 + ng][1][k];
                acc[i].x += a * wl.x + s * wr.x;
                acc[i].y += a * wl.y + s * wr.y;
                acc[i].z += a * wl.z + s * wr.z;
                acc[i].w += a * wl.w + s * wr.w;
            }
        }
        float4 bb = *(const float4*)&b[c0 + ct * 4];
        #pragma unroll
        for (int i = 0; i < 4; ++i) {
            int node = base + i * 16 + ng;
            if (node < n) {
                float4 o;
                o.x = fmaxf(acc[i].x + bb.x, 0.f);
                o.y = fmaxf(acc[i].y + bb.y, 0.f);
                o.z = fmaxf(acc[i].z + bb.z, 0.f);
                o.w = fmaxf(acc[i].w + bb.w, 0.f);
                *(float4*)&h[(size_t)node * FEAT + c0 + ct * 4] = o;
            }
        }
    }
}

// ---------------------------------------------------------------------------
// GEMM layer2 + softmax: out = softmax(agg@Wl + h@Wr + b), 64 cols.
// 64 nodes/block-iter; thread tile = 4 nodes x 4 cols; softmax across 16 lanes.
__global__ __launch_bounds__(256, 1) void gemm2_kernel(
    const unsigned* __restrict__ agg, const float* __restrict__ hbuf,
    const float* __restrict__ Wl, const float* __restrict__ Wr,
    const float* __restrict__ b, float* __restrict__ out, int n) {
    __shared__ float sWl[FEAT * OUTF];
    __shared__ float sWr[FEAT * OUTF];
    __shared__ float rows[64][2][132];
    const int tid = threadIdx.x;

    for (int i = tid * 4; i < FEAT * OUTF; i += 256 * 4) {
        *(float4*)&sWl[i] = *(const float4*)&Wl[i];
        *(float4*)&sWr[i] = *(const float4*)&Wr[i];
    }

    const int ct = tid & 15;
    const int ng = tid >> 4;

    for (int base = blockIdx.x * 64; base < n; base += gridDim.x * 64) {
        __syncthreads();
        for (int j = tid; j < 4096; j += 256) {
            int ns = j >> 6;
            int r = (j >> 5) & 1;
            int kk = (j & 31) * 4;
            int node = base + ns;
            float4 v = make_float4(0.f, 0.f, 0.f, 0.f);
            if (node < n) {
                if (r == 0) {
                    uint2 u = *(const uint2*)&agg[(size_t)node * (FEAT / 2) + (kk >> 1)];
                    v.x = __uint_as_float(u.x << 16);
                    v.y = __uint_as_float(u.x & 0xffff0000u);
                    v.z = __uint_as_float(u.y << 16);
                    v.w = __uint_as_float(u.y & 0xffff0000u);
                } else {
                    v = *(const float4*)&hbuf[(size_t)node * FEAT + kk];
                }
            }
            *(float4*)&rows[ns][r][kk] = v;
        }
        __syncthreads();

        float4 acc[4];
        #pragma unroll
        for (int i = 0; i < 4; ++i) acc[i] = make_float4(0.f, 0.f, 0.f, 0.f);
        #pragma unroll 4
        for (int k = 0; k < FEAT; ++k) {
            float4 wl = *(const float4*)&sWl[k * OUTF + ct * 4];
            float4 wr = *(const float4*)&sWr[k * OUTF + ct * 4];
            #pragma unroll
            for (int i = 0; i < 4; ++i) {
                float a = rows[i * 16 + ng][0][k];
                float s = rows[i * 16 + ng][1][k];
                acc[i].x += a * wl.x + s * wr.x;
                acc[i].y += a * wl.y + s * wr.y;
                acc[i].z += a * wl.z + s * wr.z;
                acc[i].w += a * wl.w + s * wr.w;
            }
        }
        float4 bb = *(const float4*)&b[ct * 4];
        #pragma unroll
        for (int i = 0; i < 4; ++i) {
            int node = base + i * 16 + ng;
            float4 v;
            v.x = acc[i].x + bb.x; v.y = acc[i].y + bb.y;
            v.z = acc[i].z + bb.z; v.w = acc[i].w + bb.w;
            float m = fmaxf(fmaxf(v.x, v.y), fmaxf(v.z, v.w));
            #pragma unroll
            for (int off = 8; off > 0; off >>= 1)
                m = fmaxf(m, __shfl_xor(m, off, 16));
            float4 e;
            e.x = __expf(v.x - m); e.y = __expf(v.y - m);
            e.z = __expf(v.z - m); e.w = __expf(v.w - m);
            float s = e.x + e.y + e.z + e.w;
            #pragma unroll
            for (int off = 8; off > 0; off >>= 1)
                s += __shfl_xor(s, off, 16);
            float inv = 1.0f / s;
            e.x *= inv; e.y *= inv; e.z *= inv; e.w *= inv;
            if (node < n) *(float4*)&out[(size_t)node * OUTF + ct * 4] = e;
        }
    }
}

// ---------------------------------------------------------------------------
extern "C" void kernel_launch(void* const* d_in, const int* in_sizes, int n_in,
                              void* d_out, int out_size, void* d_ws, size_t ws_size,
                              hipStream_t stream) {
    const float* x   = (const float*)d_in[0];
    const float* W1l = (const float*)d_in[1];
    const float* W1r = (const float*)d_in[2];
    const float* b1  = (const float*)d_in[3];
    const float* W2l = (const float*)d_in[4];
    const float* W2r = (const float*)d_in[5];
    const float* b2  = (const float*)d_in[6];
    const void*  ei1 = d_in[7];
    const void*  ei2 = d_in[8];
    float* out = (float*)d_out;

    const int n  = in_sizes[0] / FEAT;   // 100000
    const int e1 = in_sizes[7] / 2;      // 1600000
    const int e2 = in_sizes[8] / 2;

    // Workspace: [flag 256B][h n*128 f32][agg n*64 u32(bf16x2)][rp n u32][esrc E i32]
    char* ws = (char*)d_ws;
    const size_t hBytes  = (size_t)n * FEAT * 4;
    const size_t aggBytes = ((size_t)n * (FEAT / 2) * 4 + 255) & ~(size_t)255;
    const size_t rpBytes = (((size_t)n * 4) + 255) & ~(size_t)255;
    const int emax = (e1 > e2) ? e1 : e2;
    unsigned* flag = (unsigned*)ws;
    float*    h    = (float*)(ws + 256);
    unsigned* agg  = (unsigned*)(ws + 256 + hBytes);
    unsigned* rp   = (unsigned*)(ws + 256 + hBytes + aggBytes);
    int*      esrc = (int*)(ws + 256 + hBytes + aggBytes + rpBytes);
    if (ws_size < 256 + hBytes + aggBytes + rpBytes + (size_t)emax * 4) return;

    hipMemsetAsync(flag, 0, 4, stream);
    detect_idx_kernel<<<1, 256, 0, stream>>>((const unsigned*)ei1, flag);

    const int gatherGrid = (n + 3) / 4;          // one wave per node
    const int gemmChunks = (n + 63) / 64;

    // ---- layer 1 ----
    hipMemsetAsync(rp, 0, (size_t)n * 4, stream);
    hist_kernel<<<2048, 256, 0, stream>>>(ei1, rp, flag, e1);
    scan_kernel<<<1, 1024, 0, stream>>>(rp, n);
    fill_kernel<<<2048, 256, 0, stream>>>(ei1, rp, esrc, flag, e1);
    gather_mean_kernel<<<gatherGrid, 256, 0, stream>>>(x, rp, esrc, agg, n);
    gemm1_kernel<<<gemmChunks * 2, 256, 0, stream>>>(agg, x, W1l, W1r, b1, h, n);

    // ---- layer 2 ----
    hipMemsetAsync(rp, 0, (size_t)n * 4, stream);
    hist_kernel<<<2048, 256, 0, stream>>>(ei2, rp, flag, e2);
    scan_kernel<<<1, 1024, 0, stream>>>(rp, n);
    fill_kernel<<<2048, 256, 0, stream>>>(ei2, rp, esrc, flag, e2);
    gather_mean_kernel<<<gatherGrid, 256, 0, stream>>>(h, rp, esrc, agg, n);
    gemm2_kernel<<<gemmChunks, 256, 0, stream>>>(agg, h, W2l, W2r, b2, out, n);
}

// Round 4
// 785.723 us; speedup vs baseline: 2.5296x; 1.5414x over previous
//
#include <hip/hip_runtime.h>

// GraphSAGE 2-layer, bf16 feature plane + MFMA GEMMs:
//   convert x->bf16; per layer: hist -> scan -> fill (CSR) -> gather_mean(bf16)
//   -> MFMA GEMM (K=256 concat [agg|feat] @ [Wl;Wr], B-frags in registers).
// N=100000, E=1600000, IN=HID=128, OUT=64; edge_index int32 or int64.

#define FEAT 128
#define OUTF 64

typedef __attribute__((ext_vector_type(8))) short bf16x8;
typedef __attribute__((ext_vector_type(4))) float f32x4;

__device__ __forceinline__ unsigned f2bf_rne(float f) {
    unsigned u = __float_as_uint(f);
    return (u + 0x7fffu + ((u >> 16) & 1u)) >> 16;
}

// ---------------------------------------------------------------------------
// int64 vs int32 detection: indices < 100000 so int64 => odd 32-bit words all 0.
__global__ void detect_idx_kernel(const unsigned* __restrict__ ei, unsigned* __restrict__ flag) {
    unsigned v = ei[2 * threadIdx.x + 1];
    if (v != 0u) atomicOr(flag, 1u);
}

// ---------------------------------------------------------------------------
__global__ __launch_bounds__(256) void convert_kernel(
    const float* __restrict__ in, unsigned short* __restrict__ outb, int total4) {
    for (int i = blockIdx.x * 256 + threadIdx.x; i < total4; i += gridDim.x * 256) {
        float4 v = *(const float4*)&in[(size_t)i * 4];
        ushort4 o;
        o.x = (unsigned short)f2bf_rne(v.x);
        o.y = (unsigned short)f2bf_rne(v.y);
        o.z = (unsigned short)f2bf_rne(v.z);
        o.w = (unsigned short)f2bf_rne(v.w);
        *(ushort4*)&outb[(size_t)i * 4] = o;
    }
}

// ---------------------------------------------------------------------------
__global__ __launch_bounds__(256) void hist_kernel(
    const void* __restrict__ ei_raw, unsigned* __restrict__ rp,
    const unsigned* __restrict__ flag, int nedge) {
    const bool is32 = (*flag != 0u);
    for (int e = blockIdx.x * blockDim.x + threadIdx.x; e < nedge;
         e += gridDim.x * blockDim.x) {
        int dst = is32 ? ((const int*)ei_raw)[nedge + e]
                       : (int)((const long long*)ei_raw)[nedge + e];
        atomicAdd(&rp[dst], 1u);
    }
}

// ---------------------------------------------------------------------------
// In-place exclusive scan of rp[0..n). Single block, 1024 threads.
__global__ __launch_bounds__(1024) void scan_kernel(unsigned* __restrict__ rp, int n) {
    __shared__ unsigned wsum[16], woff[16], s_total;
    const int tid = threadIdx.x;
    const int lane = tid & 63;
    unsigned carry = 0;
    for (int base = 0; base < n; base += 1024) {
        int i = base + tid;
        unsigned v = (i < n) ? rp[i] : 0u;
        unsigned incl = v;
        #pragma unroll
        for (int off = 1; off < 64; off <<= 1) {
            unsigned t = __shfl_up(incl, off, 64);
            if (lane >= off) incl += t;
        }
        if (lane == 63) wsum[tid >> 6] = incl;
        __syncthreads();
        if (tid == 0) {
            unsigned s = 0;
            #pragma unroll
            for (int w = 0; w < 16; ++w) { unsigned t = wsum[w]; woff[w] = s; s += t; }
            s_total = s;
        }
        __syncthreads();
        if (i < n) rp[i] = carry + woff[tid >> 6] + incl - v;
        carry += s_total;
        __syncthreads();
    }
}

// ---------------------------------------------------------------------------
// Fill CSR; atomicAdd turns row starts into row ENDS (start_i = rp[i-1]).
__global__ __launch_bounds__(256) void fill_kernel(
    const void* __restrict__ ei_raw, unsigned* __restrict__ rp,
    int* __restrict__ esrc, const unsigned* __restrict__ flag, int nedge) {
    const bool is32 = (*flag != 0u);
    for (int e = blockIdx.x * blockDim.x + threadIdx.x; e < nedge;
         e += gridDim.x * blockDim.x) {
        int src, dst;
        if (is32) {
            const int* ei = (const int*)ei_raw;
            src = ei[e]; dst = ei[nedge + e];
        } else {
            const long long* ei = (const long long*)ei_raw;
            src = (int)ei[e]; dst = (int)ei[nedge + e];
        }
        unsigned pos = atomicAdd(&rp[dst], 1u);
        esrc[pos] = src;
    }
}

// ---------------------------------------------------------------------------
// Mean-gather over bf16 features: one wave per node, lane owns 2 features (4B).
__global__ __launch_bounds__(256) void gather_mean_kernel(
    const unsigned* __restrict__ featb, const unsigned* __restrict__ rp,
    const int* __restrict__ esrc, unsigned* __restrict__ agg, int n) {
    const int wave = threadIdx.x >> 6;
    const int lane = threadIdx.x & 63;
    for (int node = blockIdx.x * 4 + wave; node < n; node += gridDim.x * 4) {
        unsigned rs = node ? rp[node - 1] : 0u;
        unsigned re = rp[node];
        float ax = 0.f, ay = 0.f;
        unsigned j = rs;
        for (; j + 4 <= re; j += 4) {
            unsigned u0 = featb[(size_t)esrc[j] * 64 + lane];
            unsigned u1 = featb[(size_t)esrc[j + 1] * 64 + lane];
            unsigned u2 = featb[(size_t)esrc[j + 2] * 64 + lane];
            unsigned u3 = featb[(size_t)esrc[j + 3] * 64 + lane];
            ax += __uint_as_float(u0 << 16) + __uint_as_float(u1 << 16)
                + __uint_as_float(u2 << 16) + __uint_as_float(u3 << 16);
            ay += __uint_as_float(u0 & 0xffff0000u) + __uint_as_float(u1 & 0xffff0000u)
                + __uint_as_float(u2 & 0xffff0000u) + __uint_as_float(u3 & 0xffff0000u);
        }
        for (; j < re; ++j) {
            unsigned u = featb[(size_t)esrc[j] * 64 + lane];
            ax += __uint_as_float(u << 16);
            ay += __uint_as_float(u & 0xffff0000u);
        }
        float inv = (re > rs) ? 1.0f / (float)(re - rs) : 0.0f;
        ax *= inv; ay *= inv;
        agg[(size_t)node * 64 + lane] = f2bf_rne(ax) | (f2bf_rne(ay) << 16);
    }
}

// ---------------------------------------------------------------------------
// GEMM1 (MFMA): hb = relu([agg|xb] @ [Wl;Wr] + b), M=n, N=128, K=256, bf16 out.
// 4 waves: wave = (cg = col half, ms = node subtile). B-frags in registers.
__global__ __launch_bounds__(256, 2) void gemm1_kernel(
    const unsigned short* __restrict__ agg, const unsigned short* __restrict__ xb,
    const float* __restrict__ Wl, const float* __restrict__ Wr,
    const float* __restrict__ b, unsigned short* __restrict__ hb, int n) {
    __shared__ __align__(16) unsigned short sB[256 * FEAT];   // frag-swizzled, 64 KB
    const int tid = threadIdx.x;

    // Stage B = [Wl;Wr] -> bf16, swizzled to fragment order:
    // frag f = (col>>4)*8 + (k>>5); lane = ((k>>3)&3)*16 + (col&15); elem = k&7.
    for (int idx = tid; idx < 256 * FEAT; idx += 256) {
        int k = idx >> 7, col = idx & 127;
        float w = (k < 128) ? Wl[k * FEAT + col] : Wr[(k - 128) * FEAT + col];
        int pos = ((col >> 4) * 8 + (k >> 5)) * 512
                + ((((k >> 3) & 3) * 16 + (col & 15)) * 8) + (k & 7);
        sB[pos] = (unsigned short)f2bf_rne(w);
    }
    __syncthreads();

    const int wv = tid >> 6, lane = tid & 63;
    const int cg = wv & 1;           // column half (0: cols 0-63, 1: 64-127)
    const int ms = wv >> 1;          // node subtile within 32-row tile
    const int g = lane >> 4, c15 = lane & 15;

    bf16x8 bf[4][8];
    #pragma unroll
    for (int ct = 0; ct < 4; ++ct)
        #pragma unroll
        for (int ks = 0; ks < 8; ++ks)
            bf[ct][ks] = *(const bf16x8*)&sB[(((cg * 4 + ct) * 8 + ks) * 64 + lane) * 8];

    float bias[4];
    #pragma unroll
    for (int ct = 0; ct < 4; ++ct) bias[ct] = b[cg * 64 + ct * 16 + c15];

    const int ntiles = (n + 31) >> 5;
    for (int tile = blockIdx.x; tile < ntiles; tile += gridDim.x) {
        const int base = tile * 32;
        const int row = base + ms * 16 + c15;
        bf16x8 af[8];
        #pragma unroll
        for (int ks = 0; ks < 8; ++ks) {
            bf16x8 a = {0, 0, 0, 0, 0, 0, 0, 0};
            if (row < n) {
                int karr = ks * 32 + g * 8;
                const unsigned short* p = (ks < 4)
                    ? &agg[(size_t)row * FEAT + karr]
                    : &xb[(size_t)row * FEAT + (karr - 128)];
                a = *(const bf16x8*)p;
            }
            af[ks] = a;
        }
        f32x4 z = {0.f, 0.f, 0.f, 0.f};
        f32x4 acc[4] = {z, z, z, z};
        #pragma unroll
        for (int ks = 0; ks < 8; ++ks)
            #pragma unroll
            for (int ct = 0; ct < 4; ++ct)
                acc[ct] = __builtin_amdgcn_mfma_f32_16x16x32_bf16(
                    af[ks], bf[ct][ks], acc[ct], 0, 0, 0);
        #pragma unroll
        for (int ct = 0; ct < 4; ++ct) {
            const int col = cg * 64 + ct * 16 + c15;
            #pragma unroll
            for (int r = 0; r < 4; ++r) {
                int node = base + ms * 16 + g * 4 + r;
                if (node < n) {
                    float v = fmaxf(acc[ct][r] + bias[ct], 0.f);
                    hb[(size_t)node * FEAT + col] = (unsigned short)f2bf_rne(v);
                }
            }
        }
    }
}

// ---------------------------------------------------------------------------
// GEMM2 (MFMA) + softmax: out = softmax([agg|hb] @ [Wl;Wr] + b), N=64, f32 out.
// 4 waves = 4 node subtiles; each wave covers all 64 cols (4 col-tiles).
__global__ __launch_bounds__(256, 2) void gemm2_kernel(
    const unsigned short* __restrict__ agg, const unsigned short* __restrict__ hb,
    const float* __restrict__ Wl, const float* __restrict__ Wr,
    const float* __restrict__ b, float* __restrict__ out, int n) {
    __shared__ __align__(16) unsigned short sB[256 * OUTF];   // 32 KB
    const int tid = threadIdx.x;

    for (int idx = tid; idx < 256 * OUTF; idx += 256) {
        int k = idx >> 6, col = idx & 63;
        float w = (k < 128) ? Wl[k * OUTF + col] : Wr[(k - 128) * OUTF + col];
        int pos = ((col >> 4) * 8 + (k >> 5)) * 512
                + ((((k >> 3) & 3) * 16 + (col & 15)) * 8) + (k & 7);
        sB[pos] = (unsigned short)f2bf_rne(w);
    }
    __syncthreads();

    const int wv = tid >> 6, lane = tid & 63;
    const int g = lane >> 4, c15 = lane & 15;

    bf16x8 bf[4][8];
    #pragma unroll
    for (int ct = 0; ct < 4; ++ct)
        #pragma unroll
        for (int ks = 0; ks < 8; ++ks)
            bf[ct][ks] = *(const bf16x8*)&sB[((ct * 8 + ks) * 64 + lane) * 8];

    float bias[4];
    #pragma unroll
    for (int ct = 0; ct < 4; ++ct) bias[ct] = b[ct * 16 + c15];

    const int ntiles = (n + 63) >> 6;
    for (int tile = blockIdx.x; tile < ntiles; tile += gridDim.x) {
        const int base = tile * 64;
        const int row = base + wv * 16 + c15;
        bf16x8 af[8];
        #pragma unroll
        for (int ks = 0; ks < 8; ++ks) {
            bf16x8 a = {0, 0, 0, 0, 0, 0, 0, 0};
            if (row < n) {
                int karr = ks * 32 + g * 8;
                const unsigned short* p = (ks < 4)
                    ? &agg[(size_t)row * FEAT + karr]
                    : &hb[(size_t)row * FEAT + (karr - 128)];
                a = *(const bf16x8*)p;
            }
            af[ks] = a;
        }
        f32x4 z = {0.f, 0.f, 0.f, 0.f};
        f32x4 acc[4] = {z, z, z, z};
        #pragma unroll
        for (int ks = 0; ks < 8; ++ks)
            #pragma unroll
            for (int ct = 0; ct < 4; ++ct)
                acc[ct] = __builtin_amdgcn_mfma_f32_16x16x32_bf16(
                    af[ks], bf[ct][ks], acc[ct], 0, 0, 0);

        #pragma unroll
        for (int r = 0; r < 4; ++r) {
            float v0 = acc[0][r] + bias[0];
            float v1 = acc[1][r] + bias[1];
            float v2 = acc[2][r] + bias[2];
            float v3 = acc[3][r] + bias[3];
            float m = fmaxf(fmaxf(v0, v1), fmaxf(v2, v3));
            #pragma unroll
            for (int off = 8; off > 0; off >>= 1)
                m = fmaxf(m, __shfl_xor(m, off, 64));
            float e0 = __expf(v0 - m), e1 = __expf(v1 - m);
            float e2 = __expf(v2 - m), e3 = __expf(v3 - m);
            float s = e0 + e1 + e2 + e3;
            #pragma unroll
            for (int off = 8; off > 0; off >>= 1)
                s += __shfl_xor(s, off, 64);
            float inv = 1.0f / s;
            int node = base + wv * 16 + g * 4 + r;
            if (node < n) {
                out[(size_t)node * OUTF + c15]      = e0 * inv;
                out[(size_t)node * OUTF + 16 + c15] = e1 * inv;
                out[(size_t)node * OUTF + 32 + c15] = e2 * inv;
                out[(size_t)node * OUTF + 48 + c15] = e3 * inv;
            }
        }
    }
}

// ---------------------------------------------------------------------------
extern "C" void kernel_launch(void* const* d_in, const int* in_sizes, int n_in,
                              void* d_out, int out_size, void* d_ws, size_t ws_size,
                              hipStream_t stream) {
    const float* x   = (const float*)d_in[0];
    const float* W1l = (const float*)d_in[1];
    const float* W1r = (const float*)d_in[2];
    const float* b1  = (const float*)d_in[3];
    const float* W2l = (const float*)d_in[4];
    const float* W2r = (const float*)d_in[5];
    const float* b2  = (const float*)d_in[6];
    const void*  ei1 = d_in[7];
    const void*  ei2 = d_in[8];
    float* out = (float*)d_out;

    const int n  = in_sizes[0] / FEAT;   // 100000
    const int e1 = in_sizes[7] / 2;      // 1600000
    const int e2 = in_sizes[8] / 2;

    // Workspace: [flag 256B][xb n*128 bf16][hb n*128 bf16][agg n*128 bf16]
    //            [rp n u32 pad][esrc E i32]  ~= 84 MB
    char* ws = (char*)d_ws;
    const size_t fBytes  = (size_t)n * FEAT * 2;
    const size_t rpBytes = (((size_t)n * 4) + 255) & ~(size_t)255;
    const int emax = (e1 > e2) ? e1 : e2;
    unsigned*       flag = (unsigned*)ws;
    unsigned short* xb   = (unsigned short*)(ws + 256);
    unsigned short* hb   = (unsigned short*)(ws + 256 + fBytes);
    unsigned short* agg  = (unsigned short*)(ws + 256 + 2 * fBytes);
    unsigned*       rp   = (unsigned*)(ws + 256 + 3 * fBytes);
    int*            esrc = (int*)(ws + 256 + 3 * fBytes + rpBytes);
    if (ws_size < 256 + 3 * fBytes + rpBytes + (size_t)emax * 4) return;

    hipMemsetAsync(flag, 0, 4, stream);
    detect_idx_kernel<<<1, 256, 0, stream>>>((const unsigned*)ei1, flag);
    convert_kernel<<<2048, 256, 0, stream>>>(x, xb, in_sizes[0] / 4);

    const int gatherGrid = (n + 3) / 4;

    // ---- layer 1 ----
    hipMemsetAsync(rp, 0, (size_t)n * 4, stream);
    hist_kernel<<<2048, 256, 0, stream>>>(ei1, rp, flag, e1);
    scan_kernel<<<1, 1024, 0, stream>>>(rp, n);
    fill_kernel<<<2048, 256, 0, stream>>>(ei1, rp, esrc, flag, e1);
    gather_mean_kernel<<<gatherGrid, 256, 0, stream>>>((const unsigned*)xb, rp, esrc,
                                                       (unsigned*)agg, n);
    gemm1_kernel<<<640, 256, 0, stream>>>(agg, xb, W1l, W1r, b1, hb, n);

    // ---- layer 2 ----
    hipMemsetAsync(rp, 0, (size_t)n * 4, stream);
    hist_kernel<<<2048, 256, 0, stream>>>(ei2, rp, flag, e2);
    scan_kernel<<<1, 1024, 0, stream>>>(rp, n);
    fill_kernel<<<2048, 256, 0, stream>>>(ei2, rp, esrc, flag, e2);
    gather_mean_kernel<<<gatherGrid, 256, 0, stream>>>((const unsigned*)hb, rp, esrc,
                                                       (unsigned*)agg, n);
    gemm2_kernel<<<512, 256, 0, stream>>>(agg, hb, W2l, W2r, b2, out, n);
}

// Round 5
// 334.760 us; speedup vs baseline: 5.9373x; 2.3471x over previous
//
#include <hip/hip_runtime.h>

// GraphSAGE 2-layer, bf16 feature plane + MFMA GEMMs + bucketed CSR build:
//   convert x->bf16; per layer:
//     init_cnt -> bucket (block-aggregated bucket scatter, packed u32 pairs)
//     -> csr_local (per-bucket 128-node counting sort -> rps/rpe/esrc)
//     -> gather_mean(bf16) -> MFMA GEMM (K=256 concat [agg|feat] @ [Wl;Wr]).
// N=100000, E=1600000, IN=HID=128, OUT=64; edge_index int32 or int64.

#define FEAT 128
#define OUTF 64
#define BSH 7                   // 128 nodes per bucket
#define NBMAX 1024              // max buckets supported by LDS hist

typedef __attribute__((ext_vector_type(8))) short bf16x8;
typedef __attribute__((ext_vector_type(4))) float f32x4;

__device__ __forceinline__ unsigned f2bf_rne(float f) {
    unsigned u = __float_as_uint(f);
    return (u + 0x7fffu + ((u >> 16) & 1u)) >> 16;
}

// ---------------------------------------------------------------------------
// int64 vs int32 detection: indices < 100000 so int64 => odd 32-bit words all 0.
__global__ void detect_idx_kernel(const unsigned* __restrict__ ei, unsigned* __restrict__ flag) {
    unsigned v = ei[2 * threadIdx.x + 1];
    if (v != 0u) atomicOr(flag, 1u);
}

// ---------------------------------------------------------------------------
__global__ __launch_bounds__(256) void convert_kernel(
    const float* __restrict__ in, unsigned short* __restrict__ outb, int total4) {
    for (int i = blockIdx.x * 256 + threadIdx.x; i < total4; i += gridDim.x * 256) {
        float4 v = *(const float4*)&in[(size_t)i * 4];
        ushort4 o;
        o.x = (unsigned short)f2bf_rne(v.x);
        o.y = (unsigned short)f2bf_rne(v.y);
        o.z = (unsigned short)f2bf_rne(v.z);
        o.w = (unsigned short)f2bf_rne(v.w);
        *(ushort4*)&outb[(size_t)i * 4] = o;
    }
}

// ---------------------------------------------------------------------------
__global__ __launch_bounds__(256) void init_cnt_kernel(
    unsigned* __restrict__ cnt, unsigned cap, int nb) {
    int i = blockIdx.x * 256 + threadIdx.x;
    if (i < nb) cnt[i] = (unsigned)i * cap;
}

// ---------------------------------------------------------------------------
// Bucket scatter: each block owns a contiguous edge chunk. Phase 1: LDS
// histogram over nb buckets. Phase 2: one global atomicAdd per (block,bucket)
// reserves a contiguous run. Phase 3: scatter packed (dst_local<<17 | src)
// into the run via LDS running offsets -> ~64B contiguous write runs.
__global__ __launch_bounds__(256) void bucket_kernel(
    const void* __restrict__ ei_raw, unsigned* __restrict__ pairs,
    unsigned* __restrict__ cnt, const unsigned* __restrict__ flag,
    int nedge, unsigned cap, int nb, int chunk) {
    __shared__ unsigned hist[NBMAX];
    __shared__ unsigned offs[NBMAX];
    const int tid = threadIdx.x;
    const bool is32 = (*flag != 0u);
    const int e0 = blockIdx.x * chunk;
    const int e1 = min(e0 + chunk, nedge);
    if (e0 >= nedge) return;

    for (int i = tid; i < nb; i += 256) hist[i] = 0u;
    __syncthreads();
    for (int e = e0 + tid; e < e1; e += 256) {
        int dst = is32 ? ((const int*)ei_raw)[nedge + e]
                       : (int)((const long long*)ei_raw)[nedge + e];
        atomicAdd(&hist[(unsigned)dst >> BSH], 1u);
    }
    __syncthreads();
    for (int i = tid; i < nb; i += 256) {
        unsigned c = hist[i];
        offs[i] = c ? atomicAdd(&cnt[i], c) : 0u;
    }
    __syncthreads();
    for (int e = e0 + tid; e < e1; e += 256) {
        int src, dst;
        if (is32) {
            const int* ei = (const int*)ei_raw;
            src = ei[e]; dst = ei[nedge + e];
        } else {
            const long long* ei = (const long long*)ei_raw;
            src = (int)ei[e]; dst = (int)ei[nedge + e];
        }
        unsigned b = (unsigned)dst >> BSH;
        unsigned pos = atomicAdd(&offs[b], 1u);
        if (pos < (b + 1u) * cap)   // statistically never overflows
            pairs[pos] = (((unsigned)dst & 127u) << 17) | (unsigned)src;
    }
}

// ---------------------------------------------------------------------------
// Per-bucket counting sort: one block per bucket (128 local nodes).
// Emits rps/rpe (global esrc start/end per node) and bucket-local sorted esrc.
__global__ __launch_bounds__(256) void csr_local_kernel(
    const unsigned* __restrict__ pairs, const unsigned* __restrict__ cnt,
    unsigned* __restrict__ rps, unsigned* __restrict__ rpe,
    int* __restrict__ esrc, unsigned cap, int n) {
    __shared__ unsigned hist[128], excl[128], offs[128];
    const int b = blockIdx.x;
    const int tid = threadIdx.x;
    const unsigned base = (unsigned)b * cap;
    unsigned count = cnt[b] - base;
    if (count > cap) count = cap;

    if (tid < 128) hist[tid] = 0u;
    __syncthreads();
    for (unsigned e = tid; e < count; e += 256)
        atomicAdd(&hist[pairs[base + e] >> 17], 1u);
    __syncthreads();
    if (tid == 0) {
        unsigned s = 0;
        for (int i = 0; i < 128; ++i) { excl[i] = s; s += hist[i]; }
    }
    __syncthreads();
    if (tid < 128) {
        int node = b * 128 + tid;
        if (node < n) {
            rps[node] = base + excl[tid];
            rpe[node] = base + excl[tid] + hist[tid];
        }
        offs[tid] = excl[tid];
    }
    __syncthreads();
    for (unsigned e = tid; e < count; e += 256) {
        unsigned p = pairs[base + e];
        unsigned lpos = atomicAdd(&offs[p >> 17], 1u);
        esrc[base + lpos] = (int)(p & 0x1FFFFu);
    }
}

// ---------------------------------------------------------------------------
// Mean-gather over bf16 features: one wave per node, lane owns 2 features (4B).
__global__ __launch_bounds__(256) void gather_mean_kernel(
    const unsigned* __restrict__ featb, const unsigned* __restrict__ rps,
    const unsigned* __restrict__ rpe, const int* __restrict__ esrc,
    unsigned* __restrict__ agg, int n) {
    const int wave = threadIdx.x >> 6;
    const int lane = threadIdx.x & 63;
    for (int node = blockIdx.x * 4 + wave; node < n; node += gridDim.x * 4) {
        unsigned rs = rps[node];
        unsigned re = rpe[node];
        float ax = 0.f, ay = 0.f;
        unsigned j = rs;
        for (; j + 4 <= re; j += 4) {
            unsigned u0 = featb[(size_t)esrc[j] * 64 + lane];
            unsigned u1 = featb[(size_t)esrc[j + 1] * 64 + lane];
            unsigned u2 = featb[(size_t)esrc[j + 2] * 64 + lane];
            unsigned u3 = featb[(size_t)esrc[j + 3] * 64 + lane];
            ax += __uint_as_float(u0 << 16) + __uint_as_float(u1 << 16)
                + __uint_as_float(u2 << 16) + __uint_as_float(u3 << 16);
            ay += __uint_as_float(u0 & 0xffff0000u) + __uint_as_float(u1 & 0xffff0000u)
                + __uint_as_float(u2 & 0xffff0000u) + __uint_as_float(u3 & 0xffff0000u);
        }
        for (; j < re; ++j) {
            unsigned u = featb[(size_t)esrc[j] * 64 + lane];
            ax += __uint_as_float(u << 16);
            ay += __uint_as_float(u & 0xffff0000u);
        }
        float inv = (re > rs) ? 1.0f / (float)(re - rs) : 0.0f;
        ax *= inv; ay *= inv;
        agg[(size_t)node * 64 + lane] = f2bf_rne(ax) | (f2bf_rne(ay) << 16);
    }
}

// ---------------------------------------------------------------------------
// GEMM1 (MFMA): hb = relu([agg|xb] @ [Wl;Wr] + b), M=n, N=128, K=256, bf16 out.
__global__ __launch_bounds__(256, 2) void gemm1_kernel(
    const unsigned short* __restrict__ agg, const unsigned short* __restrict__ xb,
    const float* __restrict__ Wl, const float* __restrict__ Wr,
    const float* __restrict__ b, unsigned short* __restrict__ hb, int n) {
    __shared__ __align__(16) unsigned short sB[256 * FEAT];   // frag-swizzled, 64 KB
    const int tid = threadIdx.x;

    for (int idx = tid; idx < 256 * FEAT; idx += 256) {
        int k = idx >> 7, col = idx & 127;
        float w = (k < 128) ? Wl[k * FEAT + col] : Wr[(k - 128) * FEAT + col];
        int pos = ((col >> 4) * 8 + (k >> 5)) * 512
                + ((((k >> 3) & 3) * 16 + (col & 15)) * 8) + (k & 7);
        sB[pos] = (unsigned short)f2bf_rne(w);
    }
    __syncthreads();

    const int wv = tid >> 6, lane = tid & 63;
    const int cg = wv & 1;
    const int ms = wv >> 1;
    const int g = lane >> 4, c15 = lane & 15;

    bf16x8 bf[4][8];
    #pragma unroll
    for (int ct = 0; ct < 4; ++ct)
        #pragma unroll
        for (int ks = 0; ks < 8; ++ks)
            bf[ct][ks] = *(const bf16x8*)&sB[(((cg * 4 + ct) * 8 + ks) * 64 + lane) * 8];

    float bias[4];
    #pragma unroll
    for (int ct = 0; ct < 4; ++ct) bias[ct] = b[cg * 64 + ct * 16 + c15];

    const int ntiles = (n + 31) >> 5;
    for (int tile = blockIdx.x; tile < ntiles; tile += gridDim.x) {
        const int base = tile * 32;
        const int row = base + ms * 16 + c15;
        bf16x8 af[8];
        #pragma unroll
        for (int ks = 0; ks < 8; ++ks) {
            bf16x8 a = {0, 0, 0, 0, 0, 0, 0, 0};
            if (row < n) {
                int karr = ks * 32 + g * 8;
                const unsigned short* p = (ks < 4)
                    ? &agg[(size_t)row * FEAT + karr]
                    : &xb[(size_t)row * FEAT + (karr - 128)];
                a = *(const bf16x8*)p;
            }
            af[ks] = a;
        }
        f32x4 z = {0.f, 0.f, 0.f, 0.f};
        f32x4 acc[4] = {z, z, z, z};
        #pragma unroll
        for (int ks = 0; ks < 8; ++ks)
            #pragma unroll
            for (int ct = 0; ct < 4; ++ct)
                acc[ct] = __builtin_amdgcn_mfma_f32_16x16x32_bf16(
                    af[ks], bf[ct][ks], acc[ct], 0, 0, 0);
        #pragma unroll
        for (int ct = 0; ct < 4; ++ct) {
            const int col = cg * 64 + ct * 16 + c15;
            #pragma unroll
            for (int r = 0; r < 4; ++r) {
                int node = base + ms * 16 + g * 4 + r;
                if (node < n) {
                    float v = fmaxf(acc[ct][r] + bias[ct], 0.f);
                    hb[(size_t)node * FEAT + col] = (unsigned short)f2bf_rne(v);
                }
            }
        }
    }
}

// ---------------------------------------------------------------------------
// GEMM2 (MFMA) + softmax: out = softmax([agg|hb] @ [Wl;Wr] + b), N=64, f32 out.
__global__ __launch_bounds__(256, 2) void gemm2_kernel(
    const unsigned short* __restrict__ agg, const unsigned short* __restrict__ hb,
    const float* __restrict__ Wl, const float* __restrict__ Wr,
    const float* __restrict__ b, float* __restrict__ out, int n) {
    __shared__ __align__(16) unsigned short sB[256 * OUTF];   // 32 KB
    const int tid = threadIdx.x;

    for (int idx = tid; idx < 256 * OUTF; idx += 256) {
        int k = idx >> 6, col = idx & 63;
        float w = (k < 128) ? Wl[k * OUTF + col] : Wr[(k - 128) * OUTF + col];
        int pos = ((col >> 4) * 8 + (k >> 5)) * 512
                + ((((k >> 3) & 3) * 16 + (col & 15)) * 8) + (k & 7);
        sB[pos] = (unsigned short)f2bf_rne(w);
    }
    __syncthreads();

    const int wv = tid >> 6, lane = tid & 63;
    const int g = lane >> 4, c15 = lane & 15;

    bf16x8 bf[4][8];
    #pragma unroll
    for (int ct = 0; ct < 4; ++ct)
        #pragma unroll
        for (int ks = 0; ks < 8; ++ks)
            bf[ct][ks] = *(const bf16x8*)&sB[((ct * 8 + ks) * 64 + lane) * 8];

    float bias[4];
    #pragma unroll
    for (int ct = 0; ct < 4; ++ct) bias[ct] = b[ct * 16 + c15];

    const int ntiles = (n + 63) >> 6;
    for (int tile = blockIdx.x; tile < ntiles; tile += gridDim.x) {
        const int base = tile * 64;
        const int row = base + wv * 16 + c15;
        bf16x8 af[8];
        #pragma unroll
        for (int ks = 0; ks < 8; ++ks) {
            bf16x8 a = {0, 0, 0, 0, 0, 0, 0, 0};
            if (row < n) {
                int karr = ks * 32 + g * 8;
                const unsigned short* p = (ks < 4)
                    ? &agg[(size_t)row * FEAT + karr]
                    : &hb[(size_t)row * FEAT + (karr - 128)];
                a = *(const bf16x8*)p;
            }
            af[ks] = a;
        }
        f32x4 z = {0.f, 0.f, 0.f, 0.f};
        f32x4 acc[4] = {z, z, z, z};
        #pragma unroll
        for (int ks = 0; ks < 8; ++ks)
            #pragma unroll
            for (int ct = 0; ct < 4; ++ct)
                acc[ct] = __builtin_amdgcn_mfma_f32_16x16x32_bf16(
                    af[ks], bf[ct][ks], acc[ct], 0, 0, 0);

        #pragma unroll
        for (int r = 0; r < 4; ++r) {
            float v0 = acc[0][r] + bias[0];
            float v1 = acc[1][r] + bias[1];
            float v2 = acc[2][r] + bias[2];
            float v3 = acc[3][r] + bias[3];
            float m = fmaxf(fmaxf(v0, v1), fmaxf(v2, v3));
            #pragma unroll
            for (int off = 8; off > 0; off >>= 1)
                m = fmaxf(m, __shfl_xor(m, off, 64));
            float e0 = __expf(v0 - m), e1 = __expf(v1 - m);
            float e2 = __expf(v2 - m), e3 = __expf(v3 - m);
            float s = e0 + e1 + e2 + e3;
            #pragma unroll
            for (int off = 8; off > 0; off >>= 1)
                s += __shfl_xor(s, off, 64);
            float inv = 1.0f / s;
            int node = base + wv * 16 + g * 4 + r;
            if (node < n) {
                out[(size_t)node * OUTF + c15]      = e0 * inv;
                out[(size_t)node * OUTF + 16 + c15] = e1 * inv;
                out[(size_t)node * OUTF + 32 + c15] = e2 * inv;
                out[(size_t)node * OUTF + 48 + c15] = e3 * inv;
            }
        }
    }
}

// ---------------------------------------------------------------------------
extern "C" void kernel_launch(void* const* d_in, const int* in_sizes, int n_in,
                              void* d_out, int out_size, void* d_ws, size_t ws_size,
                              hipStream_t stream) {
    const float* x   = (const float*)d_in[0];
    const float* W1l = (const float*)d_in[1];
    const float* W1r = (const float*)d_in[2];
    const float* b1  = (const float*)d_in[3];
    const float* W2l = (const float*)d_in[4];
    const float* W2r = (const float*)d_in[5];
    const float* b2  = (const float*)d_in[6];
    const void*  ei1 = d_in[7];
    const void*  ei2 = d_in[8];
    float* out = (float*)d_out;

    const int n  = in_sizes[0] / FEAT;   // 100000
    const int e1 = in_sizes[7] / 2;      // 1600000
    const int e2 = in_sizes[8] / 2;
    const int emax = (e1 > e2) ? e1 : e2;

    const int nb = (n + 127) >> BSH;                       // 782 buckets
    if (nb > NBMAX) return;
    unsigned cap = (unsigned)(emax / nb + emax / (4 * nb) + 128);
    cap = (cap + 63u) & ~63u;                              // ~2688

    // Workspace: [flag 256B][xb][hb][agg][cnt][rps][rpe][pairs][esrc]
    char* ws = (char*)d_ws;
    const size_t fBytes   = (size_t)n * FEAT * 2;          // 25.6 MB each
    const size_t cntBytes = ((size_t)NBMAX * 4 + 255) & ~(size_t)255;
    const size_t rpBytes  = (((size_t)n * 4) + 255) & ~(size_t)255;
    const size_t bktBytes = (((size_t)nb * cap * 4) + 255) & ~(size_t)255;  // ~8.4 MB
    unsigned short* xb   = (unsigned short*)(ws + 256);
    unsigned short* hb   = (unsigned short*)(ws + 256 + fBytes);
    unsigned short* agg  = (unsigned short*)(ws + 256 + 2 * fBytes);
    unsigned*       flag = (unsigned*)ws;
    char* p = ws + 256 + 3 * fBytes;
    unsigned* cnt  = (unsigned*)p;            p += cntBytes;
    unsigned* rps  = (unsigned*)p;            p += rpBytes;
    unsigned* rpe  = (unsigned*)p;            p += rpBytes;
    unsigned* pairs = (unsigned*)p;           p += bktBytes;
    int*      esrc = (int*)p;                 p += bktBytes;
    if ((size_t)(p - ws) > ws_size) return;

    hipMemsetAsync(flag, 0, 4, stream);
    detect_idx_kernel<<<1, 256, 0, stream>>>((const unsigned*)ei1, flag);
    convert_kernel<<<2048, 256, 0, stream>>>(x, xb, in_sizes[0] / 4);

    const int gatherGrid = (n + 3) / 4;
    const int chunk1 = (e1 + 127) / 128;
    const int chunk2 = (e2 + 127) / 128;

    // ---- layer 1 ----
    init_cnt_kernel<<<(nb + 255) / 256, 256, 0, stream>>>(cnt, cap, nb);
    bucket_kernel<<<128, 256, 0, stream>>>(ei1, pairs, cnt, flag, e1, cap, nb, chunk1);
    csr_local_kernel<<<nb, 256, 0, stream>>>(pairs, cnt, rps, rpe, esrc, cap, n);
    gather_mean_kernel<<<gatherGrid, 256, 0, stream>>>((const unsigned*)xb, rps, rpe,
                                                       esrc, (unsigned*)agg, n);
    gemm1_kernel<<<640, 256, 0, stream>>>(agg, xb, W1l, W1r, b1, hb, n);

    // ---- layer 2 ----
    init_cnt_kernel<<<(nb + 255) / 256, 256, 0, stream>>>(cnt, cap, nb);
    bucket_kernel<<<128, 256, 0, stream>>>(ei2, pairs, cnt, flag, e2, cap, nb, chunk2);
    csr_local_kernel<<<nb, 256, 0, stream>>>(pairs, cnt, rps, rpe, esrc, cap, n);
    gather_mean_kernel<<<gatherGrid, 256, 0, stream>>>((const unsigned*)hb, rps, rpe,
                                                       esrc, (unsigned*)agg, n);
    gemm2_kernel<<<512, 256, 0, stream>>>(agg, hb, W2l, W2r, b2, out, n);
}

// Round 6
// 319.211 us; speedup vs baseline: 6.2265x; 1.0487x over previous
//
#include <hip/hip_runtime.h>

// GraphSAGE 2-layer, bf16 feature plane + MFMA GEMMs + bucketed CSR build.
//   Layer 1: CSR -> gather_mean128(xb) -> gemm1 (K=256 [agg|xb] @ [W1l;W1r]).
//   Layer 2: y2 = hb@W2l (MFMA); CSR -> gather_mean64(y2) -> gemm2b
//            (K=128 hb@W2r, epilogue + meanY2 + b2, softmax).
// N=100000, E=1600000, IN=HID=128, OUT=64; edge_index int32 or int64.

#define FEAT 128
#define OUTF 64
#define BSH 7                   // 128 nodes per bucket
#define NBMAX 1024              // max buckets supported by LDS hist

typedef __attribute__((ext_vector_type(8))) short bf16x8;
typedef __attribute__((ext_vector_type(4))) float f32x4;

__device__ __forceinline__ unsigned f2bf_rne(float f) {
    unsigned u = __float_as_uint(f);
    return (u + 0x7fffu + ((u >> 16) & 1u)) >> 16;
}
__device__ __forceinline__ float bf_lo(unsigned u) { return __uint_as_float(u << 16); }
__device__ __forceinline__ float bf_hi(unsigned u) { return __uint_as_float(u & 0xffff0000u); }

// ---------------------------------------------------------------------------
// int64 vs int32 detection: indices < 100000 so int64 => odd 32-bit words all 0.
__global__ void detect_idx_kernel(const unsigned* __restrict__ ei, unsigned* __restrict__ flag) {
    unsigned v = ei[2 * threadIdx.x + 1];
    if (v != 0u) atomicOr(flag, 1u);
}

// ---------------------------------------------------------------------------
__global__ __launch_bounds__(256) void convert_kernel(
    const float* __restrict__ in, unsigned short* __restrict__ outb, int total4) {
    for (int i = blockIdx.x * 256 + threadIdx.x; i < total4; i += gridDim.x * 256) {
        float4 v = *(const float4*)&in[(size_t)i * 4];
        ushort4 o;
        o.x = (unsigned short)f2bf_rne(v.x);
        o.y = (unsigned short)f2bf_rne(v.y);
        o.z = (unsigned short)f2bf_rne(v.z);
        o.w = (unsigned short)f2bf_rne(v.w);
        *(ushort4*)&outb[(size_t)i * 4] = o;
    }
}

// ---------------------------------------------------------------------------
__global__ __launch_bounds__(256) void init_cnt_kernel(
    unsigned* __restrict__ cnt, unsigned cap, int nb) {
    int i = blockIdx.x * 256 + threadIdx.x;
    if (i < nb) cnt[i] = (unsigned)i * cap;
}

// ---------------------------------------------------------------------------
// Bucket scatter: block-local LDS histogram -> one global atomicAdd per
// (block,bucket) -> packed (dst_local<<17 | src) scatter into reserved runs.
__global__ __launch_bounds__(256) void bucket_kernel(
    const void* __restrict__ ei_raw, unsigned* __restrict__ pairs,
    unsigned* __restrict__ cnt, const unsigned* __restrict__ flag,
    int nedge, unsigned cap, int nb, int chunk) {
    __shared__ unsigned hist[NBMAX];
    __shared__ unsigned offs[NBMAX];
    const int tid = threadIdx.x;
    const bool is32 = (*flag != 0u);
    const int e0 = blockIdx.x * chunk;
    const int e1 = min(e0 + chunk, nedge);
    if (e0 >= nedge) return;

    for (int i = tid; i < nb; i += 256) hist[i] = 0u;
    __syncthreads();
    for (int e = e0 + tid; e < e1; e += 256) {
        int dst = is32 ? ((const int*)ei_raw)[nedge + e]
                       : (int)((const long long*)ei_raw)[nedge + e];
        atomicAdd(&hist[(unsigned)dst >> BSH], 1u);
    }
    __syncthreads();
    for (int i = tid; i < nb; i += 256) {
        unsigned c = hist[i];
        offs[i] = c ? atomicAdd(&cnt[i], c) : 0u;
    }
    __syncthreads();
    for (int e = e0 + tid; e < e1; e += 256) {
        int src, dst;
        if (is32) {
            const int* ei = (const int*)ei_raw;
            src = ei[e]; dst = ei[nedge + e];
        } else {
            const long long* ei = (const long long*)ei_raw;
            src = (int)ei[e]; dst = (int)ei[nedge + e];
        }
        unsigned b = (unsigned)dst >> BSH;
        unsigned pos = atomicAdd(&offs[b], 1u);
        if (pos < (b + 1u) * cap)
            pairs[pos] = (((unsigned)dst & 127u) << 17) | (unsigned)src;
    }
}

// ---------------------------------------------------------------------------
// Per-bucket counting sort -> rps/rpe + bucket-local sorted esrc.
__global__ __launch_bounds__(256) void csr_local_kernel(
    const unsigned* __restrict__ pairs, const unsigned* __restrict__ cnt,
    unsigned* __restrict__ rps, unsigned* __restrict__ rpe,
    int* __restrict__ esrc, unsigned cap, int n) {
    __shared__ unsigned hist[128], excl[128], offs[128];
    const int b = blockIdx.x;
    const int tid = threadIdx.x;
    const unsigned base = (unsigned)b * cap;
    unsigned count = cnt[b] - base;
    if (count > cap) count = cap;

    if (tid < 128) hist[tid] = 0u;
    __syncthreads();
    for (unsigned e = tid; e < count; e += 256)
        atomicAdd(&hist[pairs[base + e] >> 17], 1u);
    __syncthreads();
    if (tid == 0) {
        unsigned s = 0;
        for (int i = 0; i < 128; ++i) { excl[i] = s; s += hist[i]; }
    }
    __syncthreads();
    if (tid < 128) {
        int node = b * 128 + tid;
        if (node < n) {
            rps[node] = base + excl[tid];
            rpe[node] = base + excl[tid] + hist[tid];
        }
        offs[tid] = excl[tid];
    }
    __syncthreads();
    for (unsigned e = tid; e < count; e += 256) {
        unsigned p = pairs[base + e];
        unsigned lpos = atomicAdd(&offs[p >> 17], 1u);
        esrc[base + lpos] = (int)(p & 0x1FFFFu);
    }
}

// ---------------------------------------------------------------------------
// Mean-gather over 128-wide bf16 rows: one wave per node, lane owns 2 feats.
// Unroll 8 for deep MLP.
__global__ __launch_bounds__(256) void gather_mean128_kernel(
    const unsigned* __restrict__ featb, const unsigned* __restrict__ rps,
    const unsigned* __restrict__ rpe, const int* __restrict__ esrc,
    unsigned* __restrict__ agg, int n) {
    const int wave = threadIdx.x >> 6;
    const int lane = threadIdx.x & 63;
    for (int node = blockIdx.x * 4 + wave; node < n; node += gridDim.x * 4) {
        unsigned rs = rps[node];
        unsigned re = rpe[node];
        float ax = 0.f, ay = 0.f;
        unsigned j = rs;
        for (; j + 8 <= re; j += 8) {
            int s0 = esrc[j],     s1 = esrc[j + 1], s2 = esrc[j + 2], s3 = esrc[j + 3];
            int s4 = esrc[j + 4], s5 = esrc[j + 5], s6 = esrc[j + 6], s7 = esrc[j + 7];
            unsigned u0 = featb[(size_t)s0 * 64 + lane];
            unsigned u1 = featb[(size_t)s1 * 64 + lane];
            unsigned u2 = featb[(size_t)s2 * 64 + lane];
            unsigned u3 = featb[(size_t)s3 * 64 + lane];
            unsigned u4 = featb[(size_t)s4 * 64 + lane];
            unsigned u5 = featb[(size_t)s5 * 64 + lane];
            unsigned u6 = featb[(size_t)s6 * 64 + lane];
            unsigned u7 = featb[(size_t)s7 * 64 + lane];
            ax += bf_lo(u0) + bf_lo(u1) + bf_lo(u2) + bf_lo(u3)
                + bf_lo(u4) + bf_lo(u5) + bf_lo(u6) + bf_lo(u7);
            ay += bf_hi(u0) + bf_hi(u1) + bf_hi(u2) + bf_hi(u3)
                + bf_hi(u4) + bf_hi(u5) + bf_hi(u6) + bf_hi(u7);
        }
        for (; j + 4 <= re; j += 4) {
            int s0 = esrc[j], s1 = esrc[j + 1], s2 = esrc[j + 2], s3 = esrc[j + 3];
            unsigned u0 = featb[(size_t)s0 * 64 + lane];
            unsigned u1 = featb[(size_t)s1 * 64 + lane];
            unsigned u2 = featb[(size_t)s2 * 64 + lane];
            unsigned u3 = featb[(size_t)s3 * 64 + lane];
            ax += bf_lo(u0) + bf_lo(u1) + bf_lo(u2) + bf_lo(u3);
            ay += bf_hi(u0) + bf_hi(u1) + bf_hi(u2) + bf_hi(u3);
        }
        for (; j < re; ++j) {
            unsigned u = featb[(size_t)esrc[j] * 64 + lane];
            ax += bf_lo(u); ay += bf_hi(u);
        }
        float inv = (re > rs) ? 1.0f / (float)(re - rs) : 0.0f;
        ax *= inv; ay *= inv;
        agg[(size_t)node * 64 + lane] = f2bf_rne(ax) | (f2bf_rne(ay) << 16);
    }
}

// ---------------------------------------------------------------------------
// Mean-gather over 64-wide bf16 rows (y2): one wave per node; lanes 0-31
// handle even edges, lanes 32-63 odd edges; cross-half shfl reduce at end.
__global__ __launch_bounds__(256) void gather_mean64_kernel(
    const unsigned* __restrict__ y2w, const unsigned* __restrict__ rps,
    const unsigned* __restrict__ rpe, const int* __restrict__ esrc,
    unsigned* __restrict__ aggy, int n) {
    const int wave = threadIdx.x >> 6;
    const int lane = threadIdx.x & 63;
    const int half = lane >> 5;
    const int col = lane & 31;
    for (int node = blockIdx.x * 4 + wave; node < n; node += gridDim.x * 4) {
        unsigned rs = rps[node];
        unsigned re = rpe[node];
        float ax = 0.f, ay = 0.f;
        unsigned j = rs;
        for (; j + 8 <= re; j += 8) {
            int s0 = esrc[j + half],     s1 = esrc[j + 2 + half];
            int s2 = esrc[j + 4 + half], s3 = esrc[j + 6 + half];
            unsigned u0 = y2w[(size_t)s0 * 32 + col];
            unsigned u1 = y2w[(size_t)s1 * 32 + col];
            unsigned u2 = y2w[(size_t)s2 * 32 + col];
            unsigned u3 = y2w[(size_t)s3 * 32 + col];
            ax += bf_lo(u0) + bf_lo(u1) + bf_lo(u2) + bf_lo(u3);
            ay += bf_hi(u0) + bf_hi(u1) + bf_hi(u2) + bf_hi(u3);
        }
        for (; j + 2 <= re; j += 2) {
            int s = esrc[j + half];
            unsigned u = y2w[(size_t)s * 32 + col];
            ax += bf_lo(u); ay += bf_hi(u);
        }
        if (j < re && half == 0) {
            unsigned u = y2w[(size_t)esrc[j] * 32 + col];
            ax += bf_lo(u); ay += bf_hi(u);
        }
        ax += __shfl_xor(ax, 32, 64);
        ay += __shfl_xor(ay, 32, 64);
        float inv = (re > rs) ? 1.0f / (float)(re - rs) : 0.0f;
        ax *= inv; ay *= inv;
        if (half == 0)
            aggy[(size_t)node * 32 + col] = f2bf_rne(ax) | (f2bf_rne(ay) << 16);
    }
}

// ---------------------------------------------------------------------------
// GEMM1 (MFMA): hb = relu([agg|xb] @ [W1l;W1r] + b1), N=128, K=256, bf16 out.
__global__ __launch_bounds__(256, 2) void gemm1_kernel(
    const unsigned short* __restrict__ agg, const unsigned short* __restrict__ xb,
    const float* __restrict__ Wl, const float* __restrict__ Wr,
    const float* __restrict__ b, unsigned short* __restrict__ hb, int n) {
    __shared__ __align__(16) unsigned short sB[256 * FEAT];   // 64 KB
    const int tid = threadIdx.x;

    for (int idx = tid; idx < 256 * FEAT; idx += 256) {
        int k = idx >> 7, col = idx & 127;
        float w = (k < 128) ? Wl[k * FEAT + col] : Wr[(k - 128) * FEAT + col];
        int pos = ((col >> 4) * 8 + (k >> 5)) * 512
                + ((((k >> 3) & 3) * 16 + (col & 15)) * 8) + (k & 7);
        sB[pos] = (unsigned short)f2bf_rne(w);
    }
    __syncthreads();

    const int wv = tid >> 6, lane = tid & 63;
    const int cg = wv & 1;
    const int ms = wv >> 1;
    const int g = lane >> 4, c15 = lane & 15;

    bf16x8 bf[4][8];
    #pragma unroll
    for (int ct = 0; ct < 4; ++ct)
        #pragma unroll
        for (int ks = 0; ks < 8; ++ks)
            bf[ct][ks] = *(const bf16x8*)&sB[(((cg * 4 + ct) * 8 + ks) * 64 + lane) * 8];

    float bias[4];
    #pragma unroll
    for (int ct = 0; ct < 4; ++ct) bias[ct] = b[cg * 64 + ct * 16 + c15];

    const int ntiles = (n + 31) >> 5;
    for (int tile = blockIdx.x; tile < ntiles; tile += gridDim.x) {
        const int base = tile * 32;
        const int row = base + ms * 16 + c15;
        bf16x8 af[8];
        #pragma unroll
        for (int ks = 0; ks < 8; ++ks) {
            bf16x8 a = {0, 0, 0, 0, 0, 0, 0, 0};
            if (row < n) {
                int karr = ks * 32 + g * 8;
                const unsigned short* p = (ks < 4)
                    ? &agg[(size_t)row * FEAT + karr]
                    : &xb[(size_t)row * FEAT + (karr - 128)];
                a = *(const bf16x8*)p;
            }
            af[ks] = a;
        }
        f32x4 z = {0.f, 0.f, 0.f, 0.f};
        f32x4 acc[4] = {z, z, z, z};
        #pragma unroll
        for (int ks = 0; ks < 8; ++ks)
            #pragma unroll
            for (int ct = 0; ct < 4; ++ct)
                acc[ct] = __builtin_amdgcn_mfma_f32_16x16x32_bf16(
                    af[ks], bf[ct][ks], acc[ct], 0, 0, 0);
        #pragma unroll
        for (int ct = 0; ct < 4; ++ct) {
            const int col = cg * 64 + ct * 16 + c15;
            #pragma unroll
            for (int r = 0; r < 4; ++r) {
                int node = base + ms * 16 + g * 4 + r;
                if (node < n) {
                    float v = fmaxf(acc[ct][r] + bias[ct], 0.f);
                    hb[(size_t)node * FEAT + col] = (unsigned short)f2bf_rne(v);
                }
            }
        }
    }
}

// ---------------------------------------------------------------------------
// y2 = hb @ W2l (MFMA), N=64, K=128, bf16 out (no bias).
__global__ __launch_bounds__(256, 2) void gemmy2_kernel(
    const unsigned short* __restrict__ hb, const float* __restrict__ Wl,
    unsigned short* __restrict__ y2, int n) {
    __shared__ __align__(16) unsigned short sB[128 * OUTF];   // 16 KB
    const int tid = threadIdx.x;

    for (int idx = tid; idx < 128 * OUTF; idx += 256) {
        int k = idx >> 6, col = idx & 63;
        float w = Wl[k * OUTF + col];
        int pos = ((col >> 4) * 4 + (k >> 5)) * 512
                + ((((k >> 3) & 3) * 16 + (col & 15)) * 8) + (k & 7);
        sB[pos] = (unsigned short)f2bf_rne(w);
    }
    __syncthreads();

    const int wv = tid >> 6, lane = tid & 63;
    const int g = lane >> 4, c15 = lane & 15;

    bf16x8 bf[4][4];
    #pragma unroll
    for (int ct = 0; ct < 4; ++ct)
        #pragma unroll
        for (int ks = 0; ks < 4; ++ks)
            bf[ct][ks] = *(const bf16x8*)&sB[((ct * 4 + ks) * 64 + lane) * 8];

    const int ntiles = (n + 63) >> 6;
    for (int tile = blockIdx.x; tile < ntiles; tile += gridDim.x) {
        const int base = tile * 64;
        const int row = base + wv * 16 + c15;
        bf16x8 af[4];
        #pragma unroll
        for (int ks = 0; ks < 4; ++ks) {
            bf16x8 a = {0, 0, 0, 0, 0, 0, 0, 0};
            if (row < n) a = *(const bf16x8*)&hb[(size_t)row * FEAT + ks * 32 + g * 8];
            af[ks] = a;
        }
        f32x4 z = {0.f, 0.f, 0.f, 0.f};
        f32x4 acc[4] = {z, z, z, z};
        #pragma unroll
        for (int ks = 0; ks < 4; ++ks)
            #pragma unroll
            for (int ct = 0; ct < 4; ++ct)
                acc[ct] = __builtin_amdgcn_mfma_f32_16x16x32_bf16(
                    af[ks], bf[ct][ks], acc[ct], 0, 0, 0);
        #pragma unroll
        for (int ct = 0; ct < 4; ++ct) {
            const int col = ct * 16 + c15;
            #pragma unroll
            for (int r = 0; r < 4; ++r) {
                int node = base + wv * 16 + g * 4 + r;
                if (node < n)
                    y2[(size_t)node * OUTF + col] = (unsigned short)f2bf_rne(acc[ct][r]);
            }
        }
    }
}

// ---------------------------------------------------------------------------
// GEMM2b (MFMA) + softmax: out = softmax(hb@W2r + meanY2 + b2), N=64, K=128.
__global__ __launch_bounds__(256, 2) void gemm2b_kernel(
    const unsigned short* __restrict__ hb, const unsigned short* __restrict__ aggy,
    const float* __restrict__ Wr, const float* __restrict__ b,
    float* __restrict__ out, int n) {
    __shared__ __align__(16) unsigned short sB[128 * OUTF];   // 16 KB
    const int tid = threadIdx.x;

    for (int idx = tid; idx < 128 * OUTF; idx += 256) {
        int k = idx >> 6, col = idx & 63;
        float w = Wr[k * OUTF + col];
        int pos = ((col >> 4) * 4 + (k >> 5)) * 512
                + ((((k >> 3) & 3) * 16 + (col & 15)) * 8) + (k & 7);
        sB[pos] = (unsigned short)f2bf_rne(w);
    }
    __syncthreads();

    const int wv = tid >> 6, lane = tid & 63;
    const int g = lane >> 4, c15 = lane & 15;

    bf16x8 bf[4][4];
    #pragma unroll
    for (int ct = 0; ct < 4; ++ct)
        #pragma unroll
        for (int ks = 0; ks < 4; ++ks)
            bf[ct][ks] = *(const bf16x8*)&sB[((ct * 4 + ks) * 64 + lane) * 8];

    float bias[4];
    #pragma unroll
    for (int ct = 0; ct < 4; ++ct) bias[ct] = b[ct * 16 + c15];

    const int ntiles = (n + 63) >> 6;
    for (int tile = blockIdx.x; tile < ntiles; tile += gridDim.x) {
        const int base = tile * 64;
        const int row = base + wv * 16 + c15;
        bf16x8 af[4];
        #pragma unroll
        for (int ks = 0; ks < 4; ++ks) {
            bf16x8 a = {0, 0, 0, 0, 0, 0, 0, 0};
            if (row < n) a = *(const bf16x8*)&hb[(size_t)row * FEAT + ks * 32 + g * 8];
            af[ks] = a;
        }
        f32x4 z = {0.f, 0.f, 0.f, 0.f};
        f32x4 acc[4] = {z, z, z, z};
        #pragma unroll
        for (int ks = 0; ks < 4; ++ks)
            #pragma unroll
            for (int ct = 0; ct < 4; ++ct)
                acc[ct] = __builtin_amdgcn_mfma_f32_16x16x32_bf16(
                    af[ks], bf[ct][ks], acc[ct], 0, 0, 0);

        #pragma unroll
        for (int r = 0; r < 4; ++r) {
            int node = base + wv * 16 + g * 4 + r;
            bool ok = node < n;
            float v[4];
            #pragma unroll
            for (int ct = 0; ct < 4; ++ct) {
                float my = 0.f;
                if (ok) {
                    unsigned short u = aggy[(size_t)node * OUTF + ct * 16 + c15];
                    my = __uint_as_float((unsigned)u << 16);
                }
                v[ct] = acc[ct][r] + bias[ct] + my;
            }
            float m = fmaxf(fmaxf(v[0], v[1]), fmaxf(v[2], v[3]));
            #pragma unroll
            for (int off = 8; off > 0; off >>= 1)
                m = fmaxf(m, __shfl_xor(m, off, 64));
            float e0 = __expf(v[0] - m), e1 = __expf(v[1] - m);
            float e2 = __expf(v[2] - m), e3 = __expf(v[3] - m);
            float s = e0 + e1 + e2 + e3;
            #pragma unroll
            for (int off = 8; off > 0; off >>= 1)
                s += __shfl_xor(s, off, 64);
            float inv = 1.0f / s;
            if (ok) {
                out[(size_t)node * OUTF + c15]      = e0 * inv;
                out[(size_t)node * OUTF + 16 + c15] = e1 * inv;
                out[(size_t)node * OUTF + 32 + c15] = e2 * inv;
                out[(size_t)node * OUTF + 48 + c15] = e3 * inv;
            }
        }
    }
}

// ---------------------------------------------------------------------------
extern "C" void kernel_launch(void* const* d_in, const int* in_sizes, int n_in,
                              void* d_out, int out_size, void* d_ws, size_t ws_size,
                              hipStream_t stream) {
    const float* x   = (const float*)d_in[0];
    const float* W1l = (const float*)d_in[1];
    const float* W1r = (const float*)d_in[2];
    const float* b1  = (const float*)d_in[3];
    const float* W2l = (const float*)d_in[4];
    const float* W2r = (const float*)d_in[5];
    const float* b2  = (const float*)d_in[6];
    const void*  ei1 = d_in[7];
    const void*  ei2 = d_in[8];
    float* out = (float*)d_out;

    const int n  = in_sizes[0] / FEAT;   // 100000
    const int e1 = in_sizes[7] / 2;      // 1600000
    const int e2 = in_sizes[8] / 2;
    const int emax = (e1 > e2) ? e1 : e2;

    const int nb = (n + 127) >> BSH;                       // 782 buckets
    if (nb > NBMAX) return;
    unsigned cap = (unsigned)(emax / nb + emax / (4 * nb) + 128);
    cap = (cap + 63u) & ~63u;

    // Workspace: [flag 256B][xb][hb][agg(=y2|aggy)][cnt][rps][rpe][pairs][esrc]
    char* ws = (char*)d_ws;
    const size_t fBytes   = (size_t)n * FEAT * 2;          // 25.6 MB each
    const size_t cntBytes = ((size_t)NBMAX * 4 + 255) & ~(size_t)255;
    const size_t rpBytes  = (((size_t)n * 4) + 255) & ~(size_t)255;
    const size_t bktBytes = (((size_t)nb * cap * 4) + 255) & ~(size_t)255;
    unsigned*       flag = (unsigned*)ws;
    unsigned short* xb   = (unsigned short*)(ws + 256);
    unsigned short* hb   = (unsigned short*)(ws + 256 + fBytes);
    unsigned short* agg  = (unsigned short*)(ws + 256 + 2 * fBytes);
    unsigned short* y2   = agg;                         // reused after gemm1
    unsigned short* aggy = agg + (size_t)n * OUTF;      // second half of agg region
    char* p = ws + 256 + 3 * fBytes;
    unsigned* cnt  = (unsigned*)p;            p += cntBytes;
    unsigned* rps  = (unsigned*)p;            p += rpBytes;
    unsigned* rpe  = (unsigned*)p;            p += rpBytes;
    unsigned* pairs = (unsigned*)p;           p += bktBytes;
    int*      esrc = (int*)p;                 p += bktBytes;
    if ((size_t)(p - ws) > ws_size) return;

    hipMemsetAsync(flag, 0, 4, stream);
    detect_idx_kernel<<<1, 256, 0, stream>>>((const unsigned*)ei1, flag);
    convert_kernel<<<2048, 256, 0, stream>>>(x, xb, in_sizes[0] / 4);

    const int gatherGrid = (n + 3) / 4;
    const int chunk1 = (e1 + 127) / 128;
    const int chunk2 = (e2 + 127) / 128;

    // ---- layer 1 ----
    init_cnt_kernel<<<(nb + 255) / 256, 256, 0, stream>>>(cnt, cap, nb);
    bucket_kernel<<<128, 256, 0, stream>>>(ei1, pairs, cnt, flag, e1, cap, nb, chunk1);
    csr_local_kernel<<<nb, 256, 0, stream>>>(pairs, cnt, rps, rpe, esrc, cap, n);
    gather_mean128_kernel<<<gatherGrid, 256, 0, stream>>>((const unsigned*)xb, rps, rpe,
                                                          esrc, (unsigned*)agg, n);
    gemm1_kernel<<<640, 256, 0, stream>>>(agg, xb, W1l, W1r, b1, hb, n);

    // ---- layer 2 ----
    init_cnt_kernel<<<(nb + 255) / 256, 256, 0, stream>>>(cnt, cap, nb);
    bucket_kernel<<<128, 256, 0, stream>>>(ei2, pairs, cnt, flag, e2, cap, nb, chunk2);
    csr_local_kernel<<<nb, 256, 0, stream>>>(pairs, cnt, rps, rpe, esrc, cap, n);
    gemmy2_kernel<<<512, 256, 0, stream>>>(hb, W2l, y2, n);
    gather_mean64_kernel<<<gatherGrid, 256, 0, stream>>>((const unsigned*)y2, rps, rpe,
                                                         esrc, (unsigned*)aggy, n);
    gemm2b_kernel<<<512, 256, 0, stream>>>(hb, aggy, W2r, b2, out, n);
}

// Round 7
// 305.263 us; speedup vs baseline: 6.5110x; 1.0457x over previous
//
#include <hip/hip_runtime.h>

// GraphSAGE 2-layer, bf16 feature plane + MFMA GEMMs + bucketed CSR build.
//   Layer 1: CSR -> gather_mean128(xb) -> gemm1 (K=256 [agg|xb] @ [W1l;W1r]).
//   Layer 2: y2 = hb@W2l (MFMA); CSR -> gather_mean64(y2) -> gemm2b
//            (K=128 hb@W2r, epilogue + meanY2 + b2, softmax).
// Gathers use 16B/lane uint4 row-slices: 4 (resp. 8) edges per load instr.
// N=100000, E=1600000, IN=HID=128, OUT=64; edge_index int32 or int64.

#define FEAT 128
#define OUTF 64
#define BSH 7                   // 128 nodes per bucket
#define NBMAX 1024              // max buckets supported by LDS hist

typedef __attribute__((ext_vector_type(8))) short bf16x8;
typedef __attribute__((ext_vector_type(4))) float f32x4;

__device__ __forceinline__ unsigned f2bf_rne(float f) {
    unsigned u = __float_as_uint(f);
    return (u + 0x7fffu + ((u >> 16) & 1u)) >> 16;
}
__device__ __forceinline__ float bf_lo(unsigned u) { return __uint_as_float(u << 16); }
__device__ __forceinline__ float bf_hi(unsigned u) { return __uint_as_float(u & 0xffff0000u); }

// ---------------------------------------------------------------------------
// int64 vs int32 detection: indices < 100000 so int64 => odd 32-bit words all 0.
__global__ void detect_idx_kernel(const unsigned* __restrict__ ei, unsigned* __restrict__ flag) {
    unsigned v = ei[2 * threadIdx.x + 1];
    if (v != 0u) atomicOr(flag, 1u);
}

// ---------------------------------------------------------------------------
__global__ __launch_bounds__(256) void convert_kernel(
    const float* __restrict__ in, unsigned short* __restrict__ outb, int total4) {
    for (int i = blockIdx.x * 256 + threadIdx.x; i < total4; i += gridDim.x * 256) {
        float4 v = *(const float4*)&in[(size_t)i * 4];
        ushort4 o;
        o.x = (unsigned short)f2bf_rne(v.x);
        o.y = (unsigned short)f2bf_rne(v.y);
        o.z = (unsigned short)f2bf_rne(v.z);
        o.w = (unsigned short)f2bf_rne(v.w);
        *(ushort4*)&outb[(size_t)i * 4] = o;
    }
}

// ---------------------------------------------------------------------------
__global__ __launch_bounds__(256) void init_cnt_kernel(
    unsigned* __restrict__ cnt, unsigned cap, int nb) {
    int i = blockIdx.x * 256 + threadIdx.x;
    if (i < nb) cnt[i] = (unsigned)i * cap;
}

// ---------------------------------------------------------------------------
// Bucket scatter: block-local LDS histogram -> one global atomicAdd per
// (block,bucket) -> packed (dst_local<<17 | src) scatter into reserved runs.
__global__ __launch_bounds__(256) void bucket_kernel(
    const void* __restrict__ ei_raw, unsigned* __restrict__ pairs,
    unsigned* __restrict__ cnt, const unsigned* __restrict__ flag,
    int nedge, unsigned cap, int nb, int chunk) {
    __shared__ unsigned hist[NBMAX];
    __shared__ unsigned offs[NBMAX];
    const int tid = threadIdx.x;
    const bool is32 = (*flag != 0u);
    const int e0 = blockIdx.x * chunk;
    const int e1 = min(e0 + chunk, nedge);
    if (e0 >= nedge) return;

    for (int i = tid; i < nb; i += 256) hist[i] = 0u;
    __syncthreads();
    for (int e = e0 + tid; e < e1; e += 256) {
        int dst = is32 ? ((const int*)ei_raw)[nedge + e]
                       : (int)((const long long*)ei_raw)[nedge + e];
        atomicAdd(&hist[(unsigned)dst >> BSH], 1u);
    }
    __syncthreads();
    for (int i = tid; i < nb; i += 256) {
        unsigned c = hist[i];
        offs[i] = c ? atomicAdd(&cnt[i], c) : 0u;
    }
    __syncthreads();
    for (int e = e0 + tid; e < e1; e += 256) {
        int src, dst;
        if (is32) {
            const int* ei = (const int*)ei_raw;
            src = ei[e]; dst = ei[nedge + e];
        } else {
            const long long* ei = (const long long*)ei_raw;
            src = (int)ei[e]; dst = (int)ei[nedge + e];
        }
        unsigned b = (unsigned)dst >> BSH;
        unsigned pos = atomicAdd(&offs[b], 1u);
        if (pos < (b + 1u) * cap)
            pairs[pos] = (((unsigned)dst & 127u) << 17) | (unsigned)src;
    }
}

// ---------------------------------------------------------------------------
// Per-bucket counting sort -> rps/rpe + bucket-local sorted esrc.
__global__ __launch_bounds__(256) void csr_local_kernel(
    const unsigned* __restrict__ pairs, const unsigned* __restrict__ cnt,
    unsigned* __restrict__ rps, unsigned* __restrict__ rpe,
    int* __restrict__ esrc, unsigned cap, int n) {
    __shared__ unsigned hist[128], excl[128], offs[128];
    const int b = blockIdx.x;
    const int tid = threadIdx.x;
    const unsigned base = (unsigned)b * cap;
    unsigned count = cnt[b] - base;
    if (count > cap) count = cap;

    if (tid < 128) hist[tid] = 0u;
    __syncthreads();
    for (unsigned e = tid; e < count; e += 256)
        atomicAdd(&hist[pairs[base + e] >> 17], 1u);
    __syncthreads();
    if (tid == 0) {
        unsigned s = 0;
        for (int i = 0; i < 128; ++i) { excl[i] = s; s += hist[i]; }
    }
    __syncthreads();
    if (tid < 128) {
        int node = b * 128 + tid;
        if (node < n) {
            rps[node] = base + excl[tid];
            rpe[node] = base + excl[tid] + hist[tid];
        }
        offs[tid] = excl[tid];
    }
    __syncthreads();
    for (unsigned e = tid; e < count; e += 256) {
        unsigned p = pairs[base + e];
        unsigned lpos = atomicAdd(&offs[p >> 17], 1u);
        esrc[base + lpos] = (int)(p & 0x1FFFFu);
    }
}

// ---------------------------------------------------------------------------
#define ACC8(v)                                                              \
    a0 += bf_lo((v).x); a1 += bf_hi((v).x);                                  \
    a2 += bf_lo((v).y); a3 += bf_hi((v).y);                                  \
    a4 += bf_lo((v).z); a5 += bf_hi((v).z);                                  \
    a6 += bf_lo((v).w); a7 += bf_hi((v).w);

// Mean-gather, 128-wide bf16 rows. Row = 16 lanes x 16B; 4 edges per load
// instruction; 16-edge main step keeps 4KB/wave in flight.
__global__ __launch_bounds__(256) void gather_mean128_kernel(
    const uint4* __restrict__ featq, const unsigned* __restrict__ rps,
    const unsigned* __restrict__ rpe, const int* __restrict__ esrc,
    uint4* __restrict__ aggq, int n) {
    const int wave = threadIdx.x >> 6;
    const int lane = threadIdx.x & 63;
    const int qi = lane >> 4;     // edge slot 0..3
    const int li = lane & 15;     // 16B block within row
    for (int node = blockIdx.x * 4 + wave; node < n; node += gridDim.x * 4) {
        unsigned rs = rps[node];
        unsigned re = rpe[node];
        float a0 = 0.f, a1 = 0.f, a2 = 0.f, a3 = 0.f;
        float a4 = 0.f, a5 = 0.f, a6 = 0.f, a7 = 0.f;
        unsigned j = rs;
        for (; j + 16 <= re; j += 16) {
            int i0 = esrc[j + qi];
            int i1 = esrc[j + 4 + qi];
            int i2 = esrc[j + 8 + qi];
            int i3 = esrc[j + 12 + qi];
            uint4 v0 = featq[(size_t)i0 * 16 + li];
            uint4 v1 = featq[(size_t)i1 * 16 + li];
            uint4 v2 = featq[(size_t)i2 * 16 + li];
            uint4 v3 = featq[(size_t)i3 * 16 + li];
            ACC8(v0); ACC8(v1); ACC8(v2); ACC8(v3);
        }
        for (; j + 8 <= re; j += 8) {
            int i0 = esrc[j + qi];
            int i1 = esrc[j + 4 + qi];
            uint4 v0 = featq[(size_t)i0 * 16 + li];
            uint4 v1 = featq[(size_t)i1 * 16 + li];
            ACC8(v0); ACC8(v1);
        }
        for (; j + 4 <= re; j += 4) {
            int i0 = esrc[j + qi];
            uint4 v0 = featq[(size_t)i0 * 16 + li];
            ACC8(v0);
        }
        unsigned rem = re - j;
        if ((unsigned)qi < rem) {
            int i0 = esrc[j + qi];
            uint4 v0 = featq[(size_t)i0 * 16 + li];
            ACC8(v0);
        }
        a0 += __shfl_xor(a0, 16, 64); a1 += __shfl_xor(a1, 16, 64);
        a2 += __shfl_xor(a2, 16, 64); a3 += __shfl_xor(a3, 16, 64);
        a4 += __shfl_xor(a4, 16, 64); a5 += __shfl_xor(a5, 16, 64);
        a6 += __shfl_xor(a6, 16, 64); a7 += __shfl_xor(a7, 16, 64);
        a0 += __shfl_xor(a0, 32, 64); a1 += __shfl_xor(a1, 32, 64);
        a2 += __shfl_xor(a2, 32, 64); a3 += __shfl_xor(a3, 32, 64);
        a4 += __shfl_xor(a4, 32, 64); a5 += __shfl_xor(a5, 32, 64);
        a6 += __shfl_xor(a6, 32, 64); a7 += __shfl_xor(a7, 32, 64);
        if (lane < 16) {
            float inv = (re > rs) ? 1.0f / (float)(re - rs) : 0.0f;
            uint4 o;
            o.x = f2bf_rne(a0 * inv) | (f2bf_rne(a1 * inv) << 16);
            o.y = f2bf_rne(a2 * inv) | (f2bf_rne(a3 * inv) << 16);
            o.z = f2bf_rne(a4 * inv) | (f2bf_rne(a5 * inv) << 16);
            o.w = f2bf_rne(a6 * inv) | (f2bf_rne(a7 * inv) << 16);
            aggq[(size_t)node * 16 + lane] = o;
        }
    }
}

// ---------------------------------------------------------------------------
// Mean-gather, 64-wide bf16 rows (y2). Row = 8 lanes x 16B; 8 edges per load.
__global__ __launch_bounds__(256) void gather_mean64_kernel(
    const uint4* __restrict__ y2q, const unsigned* __restrict__ rps,
    const unsigned* __restrict__ rpe, const int* __restrict__ esrc,
    uint4* __restrict__ aggyq, int n) {
    const int wave = threadIdx.x >> 6;
    const int lane = threadIdx.x & 63;
    const int oi = lane >> 3;     // edge slot 0..7
    const int li = lane & 7;      // 16B block within row
    for (int node = blockIdx.x * 4 + wave; node < n; node += gridDim.x * 4) {
        unsigned rs = rps[node];
        unsigned re = rpe[node];
        float a0 = 0.f, a1 = 0.f, a2 = 0.f, a3 = 0.f;
        float a4 = 0.f, a5 = 0.f, a6 = 0.f, a7 = 0.f;
        unsigned j = rs;
        for (; j + 16 <= re; j += 16) {
            int i0 = esrc[j + oi];
            int i1 = esrc[j + 8 + oi];
            uint4 v0 = y2q[(size_t)i0 * 8 + li];
            uint4 v1 = y2q[(size_t)i1 * 8 + li];
            ACC8(v0); ACC8(v1);
        }
        for (; j + 8 <= re; j += 8) {
            int i0 = esrc[j + oi];
            uint4 v0 = y2q[(size_t)i0 * 8 + li];
            ACC8(v0);
        }
        unsigned rem = re - j;
        if ((unsigned)oi < rem) {
            int i0 = esrc[j + oi];
            uint4 v0 = y2q[(size_t)i0 * 8 + li];
            ACC8(v0);
        }
        a0 += __shfl_xor(a0, 8, 64);  a1 += __shfl_xor(a1, 8, 64);
        a2 += __shfl_xor(a2, 8, 64);  a3 += __shfl_xor(a3, 8, 64);
        a4 += __shfl_xor(a4, 8, 64);  a5 += __shfl_xor(a5, 8, 64);
        a6 += __shfl_xor(a6, 8, 64);  a7 += __shfl_xor(a7, 8, 64);
        a0 += __shfl_xor(a0, 16, 64); a1 += __shfl_xor(a1, 16, 64);
        a2 += __shfl_xor(a2, 16, 64); a3 += __shfl_xor(a3, 16, 64);
        a4 += __shfl_xor(a4, 16, 64); a5 += __shfl_xor(a5, 16, 64);
        a6 += __shfl_xor(a6, 16, 64); a7 += __shfl_xor(a7, 16, 64);
        a0 += __shfl_xor(a0, 32, 64); a1 += __shfl_xor(a1, 32, 64);
        a2 += __shfl_xor(a2, 32, 64); a3 += __shfl_xor(a3, 32, 64);
        a4 += __shfl_xor(a4, 32, 64); a5 += __shfl_xor(a5, 32, 64);
        a6 += __shfl_xor(a6, 32, 64); a7 += __shfl_xor(a7, 32, 64);
        if (lane < 8) {
            float inv = (re > rs) ? 1.0f / (float)(re - rs) : 0.0f;
            uint4 o;
            o.x = f2bf_rne(a0 * inv) | (f2bf_rne(a1 * inv) << 16);
            o.y = f2bf_rne(a2 * inv) | (f2bf_rne(a3 * inv) << 16);
            o.z = f2bf_rne(a4 * inv) | (f2bf_rne(a5 * inv) << 16);
            o.w = f2bf_rne(a6 * inv) | (f2bf_rne(a7 * inv) << 16);
            aggyq[(size_t)node * 8 + lane] = o;
        }
    }
}

// ---------------------------------------------------------------------------
// GEMM1 (MFMA): hb = relu([agg|xb] @ [W1l;W1r] + b1), N=128, K=256, bf16 out.
__global__ __launch_bounds__(256, 2) void gemm1_kernel(
    const unsigned short* __restrict__ agg, const unsigned short* __restrict__ xb,
    const float* __restrict__ Wl, const float* __restrict__ Wr,
    const float* __restrict__ b, unsigned short* __restrict__ hb, int n) {
    __shared__ __align__(16) unsigned short sB[256 * FEAT];   // 64 KB
    const int tid = threadIdx.x;

    for (int idx = tid; idx < 256 * FEAT; idx += 256) {
        int k = idx >> 7, col = idx & 127;
        float w = (k < 128) ? Wl[k * FEAT + col] : Wr[(k - 128) * FEAT + col];
        int pos = ((col >> 4) * 8 + (k >> 5)) * 512
                + ((((k >> 3) & 3) * 16 + (col & 15)) * 8) + (k & 7);
        sB[pos] = (unsigned short)f2bf_rne(w);
    }
    __syncthreads();

    const int wv = tid >> 6, lane = tid & 63;
    const int cg = wv & 1;
    const int ms = wv >> 1;
    const int g = lane >> 4, c15 = lane & 15;

    bf16x8 bf[4][8];
    #pragma unroll
    for (int ct = 0; ct < 4; ++ct)
        #pragma unroll
        for (int ks = 0; ks < 8; ++ks)
            bf[ct][ks] = *(const bf16x8*)&sB[(((cg * 4 + ct) * 8 + ks) * 64 + lane) * 8];

    float bias[4];
    #pragma unroll
    for (int ct = 0; ct < 4; ++ct) bias[ct] = b[cg * 64 + ct * 16 + c15];

    const int ntiles = (n + 31) >> 5;
    for (int tile = blockIdx.x; tile < ntiles; tile += gridDim.x) {
        const int base = tile * 32;
        const int row = base + ms * 16 + c15;
        bf16x8 af[8];
        #pragma unroll
        for (int ks = 0; ks < 8; ++ks) {
            bf16x8 a = {0, 0, 0, 0, 0, 0, 0, 0};
            if (row < n) {
                int karr = ks * 32 + g * 8;
                const unsigned short* p = (ks < 4)
                    ? &agg[(size_t)row * FEAT + karr]
                    : &xb[(size_t)row * FEAT + (karr - 128)];
                a = *(const bf16x8*)p;
            }
            af[ks] = a;
        }
        f32x4 z = {0.f, 0.f, 0.f, 0.f};
        f32x4 acc[4] = {z, z, z, z};
        #pragma unroll
        for (int ks = 0; ks < 8; ++ks)
            #pragma unroll
            for (int ct = 0; ct < 4; ++ct)
                acc[ct] = __builtin_amdgcn_mfma_f32_16x16x32_bf16(
                    af[ks], bf[ct][ks], acc[ct], 0, 0, 0);
        #pragma unroll
        for (int ct = 0; ct < 4; ++ct) {
            const int col = cg * 64 + ct * 16 + c15;
            #pragma unroll
            for (int r = 0; r < 4; ++r) {
                int node = base + ms * 16 + g * 4 + r;
                if (node < n) {
                    float v = fmaxf(acc[ct][r] + bias[ct], 0.f);
                    hb[(size_t)node * FEAT + col] = (unsigned short)f2bf_rne(v);
                }
            }
        }
    }
}

// ---------------------------------------------------------------------------
// y2 = hb @ W2l (MFMA), N=64, K=128, bf16 out (no bias).
__global__ __launch_bounds__(256, 2) void gemmy2_kernel(
    const unsigned short* __restrict__ hb, const float* __restrict__ Wl,
    unsigned short* __restrict__ y2, int n) {
    __shared__ __align__(16) unsigned short sB[128 * OUTF];   // 16 KB
    const int tid = threadIdx.x;

    for (int idx = tid; idx < 128 * OUTF; idx += 256) {
        int k = idx >> 6, col = idx & 63;
        float w = Wl[k * OUTF + col];
        int pos = ((col >> 4) * 4 + (k >> 5)) * 512
                + ((((k >> 3) & 3) * 16 + (col & 15)) * 8) + (k & 7);
        sB[pos] = (unsigned short)f2bf_rne(w);
    }
    __syncthreads();

    const int wv = tid >> 6, lane = tid & 63;
    const int g = lane >> 4, c15 = lane & 15;

    bf16x8 bf[4][4];
    #pragma unroll
    for (int ct = 0; ct < 4; ++ct)
        #pragma unroll
        for (int ks = 0; ks < 4; ++ks)
            bf[ct][ks] = *(const bf16x8*)&sB[((ct * 4 + ks) * 64 + lane) * 8];

    const int ntiles = (n + 63) >> 6;
    for (int tile = blockIdx.x; tile < ntiles; tile += gridDim.x) {
        const int base = tile * 64;
        const int row = base + wv * 16 + c15;
        bf16x8 af[4];
        #pragma unroll
        for (int ks = 0; ks < 4; ++ks) {
            bf16x8 a = {0, 0, 0, 0, 0, 0, 0, 0};
            if (row < n) a = *(const bf16x8*)&hb[(size_t)row * FEAT + ks * 32 + g * 8];
            af[ks] = a;
        }
        f32x4 z = {0.f, 0.f, 0.f, 0.f};
        f32x4 acc[4] = {z, z, z, z};
        #pragma unroll
        for (int ks = 0; ks < 4; ++ks)
            #pragma unroll
            for (int ct = 0; ct < 4; ++ct)
                acc[ct] = __builtin_amdgcn_mfma_f32_16x16x32_bf16(
                    af[ks], bf[ct][ks], acc[ct], 0, 0, 0);
        #pragma unroll
        for (int ct = 0; ct < 4; ++ct) {
            const int col = ct * 16 + c15;
            #pragma unroll
            for (int r = 0; r < 4; ++r) {
                int node = base + wv * 16 + g * 4 + r;
                if (node < n)
                    y2[(size_t)node * OUTF + col] = (unsigned short)f2bf_rne(acc[ct][r]);
            }
        }
    }
}

// ---------------------------------------------------------------------------
// GEMM2b (MFMA) + softmax: out = softmax(hb@W2r + meanY2 + b2), N=64, K=128.
__global__ __launch_bounds__(256, 2) void gemm2b_kernel(
    const unsigned short* __restrict__ hb, const unsigned short* __restrict__ aggy,
    const float* __restrict__ Wr, const float* __restrict__ b,
    float* __restrict__ out, int n) {
    __shared__ __align__(16) unsigned short sB[128 * OUTF];   // 16 KB
    const int tid = threadIdx.x;

    for (int idx = tid; idx < 128 * OUTF; idx += 256) {
        int k = idx >> 6, col = idx & 63;
        float w = Wr[k * OUTF + col];
        int pos = ((col >> 4) * 4 + (k >> 5)) * 512
                + ((((k >> 3) & 3) * 16 + (col & 15)) * 8) + (k & 7);
        sB[pos] = (unsigned short)f2bf_rne(w);
    }
    __syncthreads();

    const int wv = tid >> 6, lane = tid & 63;
    const int g = lane >> 4, c15 = lane & 15;

    bf16x8 bf[4][4];
    #pragma unroll
    for (int ct = 0; ct < 4; ++ct)
        #pragma unroll
        for (int ks = 0; ks < 4; ++ks)
            bf[ct][ks] = *(const bf16x8*)&sB[((ct * 4 + ks) * 64 + lane) * 8];

    float bias[4];
    #pragma unroll
    for (int ct = 0; ct < 4; ++ct) bias[ct] = b[ct * 16 + c15];

    const int ntiles = (n + 63) >> 6;
    for (int tile = blockIdx.x; tile < ntiles; tile += gridDim.x) {
        const int base = tile * 64;
        const int row = base + wv * 16 + c15;
        bf16x8 af[4];
        #pragma unroll
        for (int ks = 0; ks < 4; ++ks) {
            bf16x8 a = {0, 0, 0, 0, 0, 0, 0, 0};
            if (row < n) a = *(const bf16x8*)&hb[(size_t)row * FEAT + ks * 32 + g * 8];
            af[ks] = a;
        }
        f32x4 z = {0.f, 0.f, 0.f, 0.f};
        f32x4 acc[4] = {z, z, z, z};
        #pragma unroll
        for (int ks = 0; ks < 4; ++ks)
            #pragma unroll
            for (int ct = 0; ct < 4; ++ct)
                acc[ct] = __builtin_amdgcn_mfma_f32_16x16x32_bf16(
                    af[ks], bf[ct][ks], acc[ct], 0, 0, 0);

        #pragma unroll
        for (int r = 0; r < 4; ++r) {
            int node = base + wv * 16 + g * 4 + r;
            bool ok = node < n;
            float v[4];
            #pragma unroll
            for (int ct = 0; ct < 4; ++ct) {
                float my = 0.f;
                if (ok) {
                    unsigned short u = aggy[(size_t)node * OUTF + ct * 16 + c15];
                    my = __uint_as_float((unsigned)u << 16);
                }
                v[ct] = acc[ct][r] + bias[ct] + my;
            }
            float m = fmaxf(fmaxf(v[0], v[1]), fmaxf(v[2], v[3]));
            #pragma unroll
            for (int off = 8; off > 0; off >>= 1)
                m = fmaxf(m, __shfl_xor(m, off, 64));
            float e0 = __expf(v[0] - m), e1 = __expf(v[1] - m);
            float e2 = __expf(v[2] - m), e3 = __expf(v[3] - m);
            float s = e0 + e1 + e2 + e3;
            #pragma unroll
            for (int off = 8; off > 0; off >>= 1)
                s += __shfl_xor(s, off, 64);
            float inv = 1.0f / s;
            if (ok) {
                out[(size_t)node * OUTF + c15]      = e0 * inv;
                out[(size_t)node * OUTF + 16 + c15] = e1 * inv;
                out[(size_t)node * OUTF + 32 + c15] = e2 * inv;
                out[(size_t)node * OUTF + 48 + c15] = e3 * inv;
            }
        }
    }
}

// ---------------------------------------------------------------------------
extern "C" void kernel_launch(void* const* d_in, const int* in_sizes, int n_in,
                              void* d_out, int out_size, void* d_ws, size_t ws_size,
                              hipStream_t stream) {
    const float* x   = (const float*)d_in[0];
    const float* W1l = (const float*)d_in[1];
    const float* W1r = (const float*)d_in[2];
    const float* b1  = (const float*)d_in[3];
    const float* W2l = (const float*)d_in[4];
    const float* W2r = (const float*)d_in[5];
    const float* b2  = (const float*)d_in[6];
    const void*  ei1 = d_in[7];
    const void*  ei2 = d_in[8];
    float* out = (float*)d_out;

    const int n  = in_sizes[0] / FEAT;   // 100000
    const int e1 = in_sizes[7] / 2;      // 1600000
    const int e2 = in_sizes[8] / 2;
    const int emax = (e1 > e2) ? e1 : e2;

    const int nb = (n + 127) >> BSH;                       // 782 buckets
    if (nb > NBMAX) return;
    unsigned cap = (unsigned)(emax / nb + emax / (4 * nb) + 128);
    cap = (cap + 63u) & ~63u;

    // Workspace: [flag 256B][xb][hb][agg(=y2|aggy)][cnt][rps][rpe][pairs][esrc]
    char* ws = (char*)d_ws;
    const size_t fBytes   = (size_t)n * FEAT * 2;          // 25.6 MB each
    const size_t cntBytes = ((size_t)NBMAX * 4 + 255) & ~(size_t)255;
    const size_t rpBytes  = (((size_t)n * 4) + 255) & ~(size_t)255;
    const size_t bktBytes = (((size_t)nb * cap * 4) + 255) & ~(size_t)255;
    unsigned*       flag = (unsigned*)ws;
    unsigned short* xb   = (unsigned short*)(ws + 256);
    unsigned short* hb   = (unsigned short*)(ws + 256 + fBytes);
    unsigned short* agg  = (unsigned short*)(ws + 256 + 2 * fBytes);
    unsigned short* y2   = agg;                         // reused after gemm1
    unsigned short* aggy = agg + (size_t)n * OUTF;      // second half of agg region
    char* p = ws + 256 + 3 * fBytes;
    unsigned* cnt  = (unsigned*)p;            p += cntBytes;
    unsigned* rps  = (unsigned*)p;            p += rpBytes;
    unsigned* rpe  = (unsigned*)p;            p += rpBytes;
    unsigned* pairs = (unsigned*)p;           p += bktBytes;
    int*      esrc = (int*)p;                 p += bktBytes;
    if ((size_t)(p - ws) > ws_size) return;

    hipMemsetAsync(flag, 0, 4, stream);
    detect_idx_kernel<<<1, 256, 0, stream>>>((const unsigned*)ei1, flag);
    convert_kernel<<<2048, 256, 0, stream>>>(x, xb, in_sizes[0] / 4);

    const int gatherGrid = (n + 3) / 4;
    const int chunk1 = (e1 + 127) / 128;
    const int chunk2 = (e2 + 127) / 128;

    // ---- layer 1 ----
    init_cnt_kernel<<<(nb + 255) / 256, 256, 0, stream>>>(cnt, cap, nb);
    bucket_kernel<<<128, 256, 0, stream>>>(ei1, pairs, cnt, flag, e1, cap, nb, chunk1);
    csr_local_kernel<<<nb, 256, 0, stream>>>(pairs, cnt, rps, rpe, esrc, cap, n);
    gather_mean128_kernel<<<gatherGrid, 256, 0, stream>>>((const uint4*)xb, rps, rpe,
                                                          esrc, (uint4*)agg, n);
    gemm1_kernel<<<640, 256, 0, stream>>>(agg, xb, W1l, W1r, b1, hb, n);

    // ---- layer 2 ----
    init_cnt_kernel<<<(nb + 255) / 256, 256, 0, stream>>>(cnt, cap, nb);
    bucket_kernel<<<128, 256, 0, stream>>>(ei2, pairs, cnt, flag, e2, cap, nb, chunk2);
    csr_local_kernel<<<nb, 256, 0, stream>>>(pairs, cnt, rps, rpe, esrc, cap, n);
    gemmy2_kernel<<<512, 256, 0, stream>>>(hb, W2l, y2, n);
    gather_mean64_kernel<<<gatherGrid, 256, 0, stream>>>((const uint4*)y2, rps, rpe,
                                                         esrc, (uint4*)aggy, n);
    gemm2b_kernel<<<512, 256, 0, stream>>>(hb, aggy, W2r, b2, out, n);
}

// Round 8
// 285.427 us; speedup vs baseline: 6.9635x; 1.0695x over previous
//
#include <hip/hip_runtime.h>

// GraphSAGE 2-layer, bf16 feature plane + MFMA GEMMs + bucketed CSR build.
//   Layer 1: CSR -> gather_mean128(xb) -> gemm1 (K=256 [agg|xb] @ [W1l;W1r]).
//   Layer 2: y2 = hb@W2l (MFMA); CSR -> gather_mean64(y2) -> gemm2b
//            (K=128 hb@W2r, epilogue + meanY2 + b2, softmax).
// Gathers use 16B/lane uint4 row-slices: 4 (resp. 8) edges per load instr.
// bucket_kernel at 512 blocks (2 blocks/CU): latency-hiding over minimal-atomic.
// N=100000, E=1600000, IN=HID=128, OUT=64; edge_index int32 or int64.

#define FEAT 128
#define OUTF 64
#define BSH 7                   // 128 nodes per bucket
#define NBMAX 1024              // max buckets supported by LDS hist
#define BUCKET_BLOCKS 512

typedef __attribute__((ext_vector_type(8))) short bf16x8;
typedef __attribute__((ext_vector_type(4))) float f32x4;

__device__ __forceinline__ unsigned f2bf_rne(float f) {
    unsigned u = __float_as_uint(f);
    return (u + 0x7fffu + ((u >> 16) & 1u)) >> 16;
}
__device__ __forceinline__ float bf_lo(unsigned u) { return __uint_as_float(u << 16); }
__device__ __forceinline__ float bf_hi(unsigned u) { return __uint_as_float(u & 0xffff0000u); }

// ---------------------------------------------------------------------------
// int64 vs int32 detection: indices < 100000 so int64 => odd 32-bit words all 0.
__global__ void detect_idx_kernel(const unsigned* __restrict__ ei, unsigned* __restrict__ flag) {
    unsigned v = ei[2 * threadIdx.x + 1];
    if (v != 0u) atomicOr(flag, 1u);
}

// ---------------------------------------------------------------------------
__global__ __launch_bounds__(256) void convert_kernel(
    const float* __restrict__ in, unsigned short* __restrict__ outb, int total4) {
    for (int i = blockIdx.x * 256 + threadIdx.x; i < total4; i += gridDim.x * 256) {
        float4 v = *(const float4*)&in[(size_t)i * 4];
        ushort4 o;
        o.x = (unsigned short)f2bf_rne(v.x);
        o.y = (unsigned short)f2bf_rne(v.y);
        o.z = (unsigned short)f2bf_rne(v.z);
        o.w = (unsigned short)f2bf_rne(v.w);
        *(ushort4*)&outb[(size_t)i * 4] = o;
    }
}

// ---------------------------------------------------------------------------
__global__ __launch_bounds__(256) void init_cnt_kernel(
    unsigned* __restrict__ cnt, unsigned cap, int nb) {
    int i = blockIdx.x * 256 + threadIdx.x;
    if (i < nb) cnt[i] = (unsigned)i * cap;
}

// ---------------------------------------------------------------------------
// Bucket scatter: block-local LDS histogram -> one global atomicAdd per
// (block,bucket) -> packed (dst_local<<17 | src) scatter into reserved runs.
__global__ __launch_bounds__(256) void bucket_kernel(
    const void* __restrict__ ei_raw, unsigned* __restrict__ pairs,
    unsigned* __restrict__ cnt, const unsigned* __restrict__ flag,
    int nedge, unsigned cap, int nb, int chunk) {
    __shared__ unsigned hist[NBMAX];
    __shared__ unsigned offs[NBMAX];
    const int tid = threadIdx.x;
    const bool is32 = (*flag != 0u);
    const int e0 = blockIdx.x * chunk;
    const int e1 = min(e0 + chunk, nedge);
    if (e0 >= nedge) return;

    for (int i = tid; i < nb; i += 256) hist[i] = 0u;
    __syncthreads();
    for (int e = e0 + tid; e < e1; e += 256) {
        int dst = is32 ? ((const int*)ei_raw)[nedge + e]
                       : (int)((const long long*)ei_raw)[nedge + e];
        atomicAdd(&hist[(unsigned)dst >> BSH], 1u);
    }
    __syncthreads();
    for (int i = tid; i < nb; i += 256) {
        unsigned c = hist[i];
        offs[i] = c ? atomicAdd(&cnt[i], c) : 0u;
    }
    __syncthreads();
    for (int e = e0 + tid; e < e1; e += 256) {
        int src, dst;
        if (is32) {
            const int* ei = (const int*)ei_raw;
            src = ei[e]; dst = ei[nedge + e];
        } else {
            const long long* ei = (const long long*)ei_raw;
            src = (int)ei[e]; dst = (int)ei[nedge + e];
        }
        unsigned b = (unsigned)dst >> BSH;
        unsigned pos = atomicAdd(&offs[b], 1u);
        if (pos < (b + 1u) * cap)
            pairs[pos] = (((unsigned)dst & 127u) << 17) | (unsigned)src;
    }
}

// ---------------------------------------------------------------------------
// Per-bucket counting sort -> rps/rpe + bucket-local sorted esrc.
__global__ __launch_bounds__(256) void csr_local_kernel(
    const unsigned* __restrict__ pairs, const unsigned* __restrict__ cnt,
    unsigned* __restrict__ rps, unsigned* __restrict__ rpe,
    int* __restrict__ esrc, unsigned cap, int n) {
    __shared__ unsigned hist[128], excl[128], offs[128];
    const int b = blockIdx.x;
    const int tid = threadIdx.x;
    const unsigned base = (unsigned)b * cap;
    unsigned count = cnt[b] - base;
    if (count > cap) count = cap;

    if (tid < 128) hist[tid] = 0u;
    __syncthreads();
    for (unsigned e = tid; e < count; e += 256)
        atomicAdd(&hist[pairs[base + e] >> 17], 1u);
    __syncthreads();
    if (tid == 0) {
        unsigned s = 0;
        for (int i = 0; i < 128; ++i) { excl[i] = s; s += hist[i]; }
    }
    __syncthreads();
    if (tid < 128) {
        int node = b * 128 + tid;
        if (node < n) {
            rps[node] = base + excl[tid];
            rpe[node] = base + excl[tid] + hist[tid];
        }
        offs[tid] = excl[tid];
    }
    __syncthreads();
    for (unsigned e = tid; e < count; e += 256) {
        unsigned p = pairs[base + e];
        unsigned lpos = atomicAdd(&offs[p >> 17], 1u);
        esrc[base + lpos] = (int)(p & 0x1FFFFu);
    }
}

// ---------------------------------------------------------------------------
#define ACC8(v)                                                              \
    a0 += bf_lo((v).x); a1 += bf_hi((v).x);                                  \
    a2 += bf_lo((v).y); a3 += bf_hi((v).y);                                  \
    a4 += bf_lo((v).z); a5 += bf_hi((v).z);                                  \
    a6 += bf_lo((v).w); a7 += bf_hi((v).w);

// Mean-gather, 128-wide bf16 rows. Row = 16 lanes x 16B; 4 edges per load
// instruction; 16-edge main step keeps 4KB/wave in flight.
__global__ __launch_bounds__(256) void gather_mean128_kernel(
    const uint4* __restrict__ featq, const unsigned* __restrict__ rps,
    const unsigned* __restrict__ rpe, const int* __restrict__ esrc,
    uint4* __restrict__ aggq, int n) {
    const int wave = threadIdx.x >> 6;
    const int lane = threadIdx.x & 63;
    const int qi = lane >> 4;     // edge slot 0..3
    const int li = lane & 15;     // 16B block within row
    for (int node = blockIdx.x * 4 + wave; node < n; node += gridDim.x * 4) {
        unsigned rs = rps[node];
        unsigned re = rpe[node];
        float a0 = 0.f, a1 = 0.f, a2 = 0.f, a3 = 0.f;
        float a4 = 0.f, a5 = 0.f, a6 = 0.f, a7 = 0.f;
        unsigned j = rs;
        for (; j + 16 <= re; j += 16) {
            int i0 = esrc[j + qi];
            int i1 = esrc[j + 4 + qi];
            int i2 = esrc[j + 8 + qi];
            int i3 = esrc[j + 12 + qi];
            uint4 v0 = featq[(size_t)i0 * 16 + li];
            uint4 v1 = featq[(size_t)i1 * 16 + li];
            uint4 v2 = featq[(size_t)i2 * 16 + li];
            uint4 v3 = featq[(size_t)i3 * 16 + li];
            ACC8(v0); ACC8(v1); ACC8(v2); ACC8(v3);
        }
        for (; j + 8 <= re; j += 8) {
            int i0 = esrc[j + qi];
            int i1 = esrc[j + 4 + qi];
            uint4 v0 = featq[(size_t)i0 * 16 + li];
            uint4 v1 = featq[(size_t)i1 * 16 + li];
            ACC8(v0); ACC8(v1);
        }
        for (; j + 4 <= re; j += 4) {
            int i0 = esrc[j + qi];
            uint4 v0 = featq[(size_t)i0 * 16 + li];
            ACC8(v0);
        }
        unsigned rem = re - j;
        if ((unsigned)qi < rem) {
            int i0 = esrc[j + qi];
            uint4 v0 = featq[(size_t)i0 * 16 + li];
            ACC8(v0);
        }
        a0 += __shfl_xor(a0, 16, 64); a1 += __shfl_xor(a1, 16, 64);
        a2 += __shfl_xor(a2, 16, 64); a3 += __shfl_xor(a3, 16, 64);
        a4 += __shfl_xor(a4, 16, 64); a5 += __shfl_xor(a5, 16, 64);
        a6 += __shfl_xor(a6, 16, 64); a7 += __shfl_xor(a7, 16, 64);
        a0 += __shfl_xor(a0, 32, 64); a1 += __shfl_xor(a1, 32, 64);
        a2 += __shfl_xor(a2, 32, 64); a3 += __shfl_xor(a3, 32, 64);
        a4 += __shfl_xor(a4, 32, 64); a5 += __shfl_xor(a5, 32, 64);
        a6 += __shfl_xor(a6, 32, 64); a7 += __shfl_xor(a7, 32, 64);
        if (lane < 16) {
            float inv = (re > rs) ? 1.0f / (float)(re - rs) : 0.0f;
            uint4 o;
            o.x = f2bf_rne(a0 * inv) | (f2bf_rne(a1 * inv) << 16);
            o.y = f2bf_rne(a2 * inv) | (f2bf_rne(a3 * inv) << 16);
            o.z = f2bf_rne(a4 * inv) | (f2bf_rne(a5 * inv) << 16);
            o.w = f2bf_rne(a6 * inv) | (f2bf_rne(a7 * inv) << 16);
            aggq[(size_t)node * 16 + lane] = o;
        }
    }
}

// ---------------------------------------------------------------------------
// Mean-gather, 64-wide bf16 rows (y2). Row = 8 lanes x 16B; 8 edges per load.
__global__ __launch_bounds__(256) void gather_mean64_kernel(
    const uint4* __restrict__ y2q, const unsigned* __restrict__ rps,
    const unsigned* __restrict__ rpe, const int* __restrict__ esrc,
    uint4* __restrict__ aggyq, int n) {
    const int wave = threadIdx.x >> 6;
    const int lane = threadIdx.x & 63;
    const int oi = lane >> 3;     // edge slot 0..7
    const int li = lane & 7;      // 16B block within row
    for (int node = blockIdx.x * 4 + wave; node < n; node += gridDim.x * 4) {
        unsigned rs = rps[node];
        unsigned re = rpe[node];
        float a0 = 0.f, a1 = 0.f, a2 = 0.f, a3 = 0.f;
        float a4 = 0.f, a5 = 0.f, a6 = 0.f, a7 = 0.f;
        unsigned j = rs;
        for (; j + 16 <= re; j += 16) {
            int i0 = esrc[j + oi];
            int i1 = esrc[j + 8 + oi];
            uint4 v0 = y2q[(size_t)i0 * 8 + li];
            uint4 v1 = y2q[(size_t)i1 * 8 + li];
            ACC8(v0); ACC8(v1);
        }
        for (; j + 8 <= re; j += 8) {
            int i0 = esrc[j + oi];
            uint4 v0 = y2q[(size_t)i0 * 8 + li];
            ACC8(v0);
        }
        unsigned rem = re - j;
        if ((unsigned)oi < rem) {
            int i0 = esrc[j + oi];
            uint4 v0 = y2q[(size_t)i0 * 8 + li];
            ACC8(v0);
        }
        a0 += __shfl_xor(a0, 8, 64);  a1 += __shfl_xor(a1, 8, 64);
        a2 += __shfl_xor(a2, 8, 64);  a3 += __shfl_xor(a3, 8, 64);
        a4 += __shfl_xor(a4, 8, 64);  a5 += __shfl_xor(a5, 8, 64);
        a6 += __shfl_xor(a6, 8, 64);  a7 += __shfl_xor(a7, 8, 64);
        a0 += __shfl_xor(a0, 16, 64); a1 += __shfl_xor(a1, 16, 64);
        a2 += __shfl_xor(a2, 16, 64); a3 += __shfl_xor(a3, 16, 64);
        a4 += __shfl_xor(a4, 16, 64); a5 += __shfl_xor(a5, 16, 64);
        a6 += __shfl_xor(a6, 16, 64); a7 += __shfl_xor(a7, 16, 64);
        a0 += __shfl_xor(a0, 32, 64); a1 += __shfl_xor(a1, 32, 64);
        a2 += __shfl_xor(a2, 32, 64); a3 += __shfl_xor(a3, 32, 64);
        a4 += __shfl_xor(a4, 32, 64); a5 += __shfl_xor(a5, 32, 64);
        a6 += __shfl_xor(a6, 32, 64); a7 += __shfl_xor(a7, 32, 64);
        if (lane < 8) {
            float inv = (re > rs) ? 1.0f / (float)(re - rs) : 0.0f;
            uint4 o;
            o.x = f2bf_rne(a0 * inv) | (f2bf_rne(a1 * inv) << 16);
            o.y = f2bf_rne(a2 * inv) | (f2bf_rne(a3 * inv) << 16);
            o.z = f2bf_rne(a4 * inv) | (f2bf_rne(a5 * inv) << 16);
            o.w = f2bf_rne(a6 * inv) | (f2bf_rne(a7 * inv) << 16);
            aggyq[(size_t)node * 8 + lane] = o;
        }
    }
}

// ---------------------------------------------------------------------------
// GEMM1 (MFMA): hb = relu([agg|xb] @ [W1l;W1r] + b1), N=128, K=256, bf16 out.
__global__ __launch_bounds__(256, 2) void gemm1_kernel(
    const unsigned short* __restrict__ agg, const unsigned short* __restrict__ xb,
    const float* __restrict__ Wl, const float* __restrict__ Wr,
    const float* __restrict__ b, unsigned short* __restrict__ hb, int n) {
    __shared__ __align__(16) unsigned short sB[256 * FEAT];   // 64 KB
    const int tid = threadIdx.x;

    for (int idx = tid; idx < 256 * FEAT; idx += 256) {
        int k = idx >> 7, col = idx & 127;
        float w = (k < 128) ? Wl[k * FEAT + col] : Wr[(k - 128) * FEAT + col];
        int pos = ((col >> 4) * 8 + (k >> 5)) * 512
                + ((((k >> 3) & 3) * 16 + (col & 15)) * 8) + (k & 7);
        sB[pos] = (unsigned short)f2bf_rne(w);
    }
    __syncthreads();

    const int wv = tid >> 6, lane = tid & 63;
    const int cg = wv & 1;
    const int ms = wv >> 1;
    const int g = lane >> 4, c15 = lane & 15;

    bf16x8 bf[4][8];
    #pragma unroll
    for (int ct = 0; ct < 4; ++ct)
        #pragma unroll
        for (int ks = 0; ks < 8; ++ks)
            bf[ct][ks] = *(const bf16x8*)&sB[(((cg * 4 + ct) * 8 + ks) * 64 + lane) * 8];

    float bias[4];
    #pragma unroll
    for (int ct = 0; ct < 4; ++ct) bias[ct] = b[cg * 64 + ct * 16 + c15];

    const int ntiles = (n + 31) >> 5;
    for (int tile = blockIdx.x; tile < ntiles; tile += gridDim.x) {
        const int base = tile * 32;
        const int row = base + ms * 16 + c15;
        bf16x8 af[8];
        #pragma unroll
        for (int ks = 0; ks < 8; ++ks) {
            bf16x8 a = {0, 0, 0, 0, 0, 0, 0, 0};
            if (row < n) {
                int karr = ks * 32 + g * 8;
                const unsigned short* p = (ks < 4)
                    ? &agg[(size_t)row * FEAT + karr]
                    : &xb[(size_t)row * FEAT + (karr - 128)];
                a = *(const bf16x8*)p;
            }
            af[ks] = a;
        }
        f32x4 z = {0.f, 0.f, 0.f, 0.f};
        f32x4 acc[4] = {z, z, z, z};
        #pragma unroll
        for (int ks = 0; ks < 8; ++ks)
            #pragma unroll
            for (int ct = 0; ct < 4; ++ct)
                acc[ct] = __builtin_amdgcn_mfma_f32_16x16x32_bf16(
                    af[ks], bf[ct][ks], acc[ct], 0, 0, 0);
        #pragma unroll
        for (int ct = 0; ct < 4; ++ct) {
            const int col = cg * 64 + ct * 16 + c15;
            #pragma unroll
            for (int r = 0; r < 4; ++r) {
                int node = base + ms * 16 + g * 4 + r;
                if (node < n) {
                    float v = fmaxf(acc[ct][r] + bias[ct], 0.f);
                    hb[(size_t)node * FEAT + col] = (unsigned short)f2bf_rne(v);
                }
            }
        }
    }
}

// ---------------------------------------------------------------------------
// y2 = hb @ W2l (MFMA), N=64, K=128, bf16 out (no bias).
__global__ __launch_bounds__(256, 2) void gemmy2_kernel(
    const unsigned short* __restrict__ hb, const float* __restrict__ Wl,
    unsigned short* __restrict__ y2, int n) {
    __shared__ __align__(16) unsigned short sB[128 * OUTF];   // 16 KB
    const int tid = threadIdx.x;

    for (int idx = tid; idx < 128 * OUTF; idx += 256) {
        int k = idx >> 6, col = idx & 63;
        float w = Wl[k * OUTF + col];
        int pos = ((col >> 4) * 4 + (k >> 5)) * 512
                + ((((k >> 3) & 3) * 16 + (col & 15)) * 8) + (k & 7);
        sB[pos] = (unsigned short)f2bf_rne(w);
    }
    __syncthreads();

    const int wv = tid >> 6, lane = tid & 63;
    const int g = lane >> 4, c15 = lane & 15;

    bf16x8 bf[4][4];
    #pragma unroll
    for (int ct = 0; ct < 4; ++ct)
        #pragma unroll
        for (int ks = 0; ks < 4; ++ks)
            bf[ct][ks] = *(const bf16x8*)&sB[((ct * 4 + ks) * 64 + lane) * 8];

    const int ntiles = (n + 63) >> 6;
    for (int tile = blockIdx.x; tile < ntiles; tile += gridDim.x) {
        const int base = tile * 64;
        const int row = base + wv * 16 + c15;
        bf16x8 af[4];
        #pragma unroll
        for (int ks = 0; ks < 4; ++ks) {
            bf16x8 a = {0, 0, 0, 0, 0, 0, 0, 0};
            if (row < n) a = *(const bf16x8*)&hb[(size_t)row * FEAT + ks * 32 + g * 8];
            af[ks] = a;
        }
        f32x4 z = {0.f, 0.f, 0.f, 0.f};
        f32x4 acc[4] = {z, z, z, z};
        #pragma unroll
        for (int ks = 0; ks < 4; ++ks)
            #pragma unroll
            for (int ct = 0; ct < 4; ++ct)
                acc[ct] = __builtin_amdgcn_mfma_f32_16x16x32_bf16(
                    af[ks], bf[ct][ks], acc[ct], 0, 0, 0);
        #pragma unroll
        for (int ct = 0; ct < 4; ++ct) {
            const int col = ct * 16 + c15;
            #pragma unroll
            for (int r = 0; r < 4; ++r) {
                int node = base + wv * 16 + g * 4 + r;
                if (node < n)
                    y2[(size_t)node * OUTF + col] = (unsigned short)f2bf_rne(acc[ct][r]);
            }
        }
    }
}

// ---------------------------------------------------------------------------
// GEMM2b (MFMA) + softmax: out = softmax(hb@W2r + meanY2 + b2), N=64, K=128.
__global__ __launch_bounds__(256, 2) void gemm2b_kernel(
    const unsigned short* __restrict__ hb, const unsigned short* __restrict__ aggy,
    const float* __restrict__ Wr, const float* __restrict__ b,
    float* __restrict__ out, int n) {
    __shared__ __align__(16) unsigned short sB[128 * OUTF];   // 16 KB
    const int tid = threadIdx.x;

    for (int idx = tid; idx < 128 * OUTF; idx += 256) {
        int k = idx >> 6, col = idx & 63;
        float w = Wr[k * OUTF + col];
        int pos = ((col >> 4) * 4 + (k >> 5)) * 512
                + ((((k >> 3) & 3) * 16 + (col & 15)) * 8) + (k & 7);
        sB[pos] = (unsigned short)f2bf_rne(w);
    }
    __syncthreads();

    const int wv = tid >> 6, lane = tid & 63;
    const int g = lane >> 4, c15 = lane & 15;

    bf16x8 bf[4][4];
    #pragma unroll
    for (int ct = 0; ct < 4; ++ct)
        #pragma unroll
        for (int ks = 0; ks < 4; ++ks)
            bf[ct][ks] = *(const bf16x8*)&sB[((ct * 4 + ks) * 64 + lane) * 8];

    float bias[4];
    #pragma unroll
    for (int ct = 0; ct < 4; ++ct) bias[ct] = b[ct * 16 + c15];

    const int ntiles = (n + 63) >> 6;
    for (int tile = blockIdx.x; tile < ntiles; tile += gridDim.x) {
        const int base = tile * 64;
        const int row = base + wv * 16 + c15;
        bf16x8 af[4];
        #pragma unroll
        for (int ks = 0; ks < 4; ++ks) {
            bf16x8 a = {0, 0, 0, 0, 0, 0, 0, 0};
            if (row < n) a = *(const bf16x8*)&hb[(size_t)row * FEAT + ks * 32 + g * 8];
            af[ks] = a;
        }
        f32x4 z = {0.f, 0.f, 0.f, 0.f};
        f32x4 acc[4] = {z, z, z, z};
        #pragma unroll
        for (int ks = 0; ks < 4; ++ks)
            #pragma unroll
            for (int ct = 0; ct < 4; ++ct)
                acc[ct] = __builtin_amdgcn_mfma_f32_16x16x32_bf16(
                    af[ks], bf[ct][ks], acc[ct], 0, 0, 0);

        #pragma unroll
        for (int r = 0; r < 4; ++r) {
            int node = base + wv * 16 + g * 4 + r;
            bool ok = node < n;
            float v[4];
            #pragma unroll
            for (int ct = 0; ct < 4; ++ct) {
                float my = 0.f;
                if (ok) {
                    unsigned short u = aggy[(size_t)node * OUTF + ct * 16 + c15];
                    my = __uint_as_float((unsigned)u << 16);
                }
                v[ct] = acc[ct][r] + bias[ct] + my;
            }
            float m = fmaxf(fmaxf(v[0], v[1]), fmaxf(v[2], v[3]));
            #pragma unroll
            for (int off = 8; off > 0; off >>= 1)
                m = fmaxf(m, __shfl_xor(m, off, 64));
            float e0 = __expf(v[0] - m), e1 = __expf(v[1] - m);
            float e2 = __expf(v[2] - m), e3 = __expf(v[3] - m);
            float s = e0 + e1 + e2 + e3;
            #pragma unroll
            for (int off = 8; off > 0; off >>= 1)
                s += __shfl_xor(s, off, 64);
            float inv = 1.0f / s;
            if (ok) {
                out[(size_t)node * OUTF + c15]      = e0 * inv;
                out[(size_t)node * OUTF + 16 + c15] = e1 * inv;
                out[(size_t)node * OUTF + 32 + c15] = e2 * inv;
                out[(size_t)node * OUTF + 48 + c15] = e3 * inv;
            }
        }
    }
}

// ---------------------------------------------------------------------------
extern "C" void kernel_launch(void* const* d_in, const int* in_sizes, int n_in,
                              void* d_out, int out_size, void* d_ws, size_t ws_size,
                              hipStream_t stream) {
    const float* x   = (const float*)d_in[0];
    const float* W1l = (const float*)d_in[1];
    const float* W1r = (const float*)d_in[2];
    const float* b1  = (const float*)d_in[3];
    const float* W2l = (const float*)d_in[4];
    const float* W2r = (const float*)d_in[5];
    const float* b2  = (const float*)d_in[6];
    const void*  ei1 = d_in[7];
    const void*  ei2 = d_in[8];
    float* out = (float*)d_out;

    const int n  = in_sizes[0] / FEAT;   // 100000
    const int e1 = in_sizes[7] / 2;      // 1600000
    const int e2 = in_sizes[8] / 2;
    const int emax = (e1 > e2) ? e1 : e2;

    const int nb = (n + 127) >> BSH;                       // 782 buckets
    if (nb > NBMAX) return;
    unsigned cap = (unsigned)(emax / nb + emax / (4 * nb) + 128);
    cap = (cap + 63u) & ~63u;

    // Workspace: [flag 256B][xb][hb][agg(=y2|aggy)][cnt][rps][rpe][pairs][esrc]
    char* ws = (char*)d_ws;
    const size_t fBytes   = (size_t)n * FEAT * 2;          // 25.6 MB each
    const size_t cntBytes = ((size_t)NBMAX * 4 + 255) & ~(size_t)255;
    const size_t rpBytes  = (((size_t)n * 4) + 255) & ~(size_t)255;
    const size_t bktBytes = (((size_t)nb * cap * 4) + 255) & ~(size_t)255;
    unsigned*       flag = (unsigned*)ws;
    unsigned short* xb   = (unsigned short*)(ws + 256);
    unsigned short* hb   = (unsigned short*)(ws + 256 + fBytes);
    unsigned short* agg  = (unsigned short*)(ws + 256 + 2 * fBytes);
    unsigned short* y2   = agg;                         // reused after gemm1
    unsigned short* aggy = agg + (size_t)n * OUTF;      // second half of agg region
    char* p = ws + 256 + 3 * fBytes;
    unsigned* cnt  = (unsigned*)p;            p += cntBytes;
    unsigned* rps  = (unsigned*)p;            p += rpBytes;
    unsigned* rpe  = (unsigned*)p;            p += rpBytes;
    unsigned* pairs = (unsigned*)p;           p += bktBytes;
    int*      esrc = (int*)p;                 p += bktBytes;
    if ((size_t)(p - ws) > ws_size) return;

    hipMemsetAsync(flag, 0, 4, stream);
    detect_idx_kernel<<<1, 256, 0, stream>>>((const unsigned*)ei1, flag);
    convert_kernel<<<2048, 256, 0, stream>>>(x, xb, in_sizes[0] / 4);

    const int gatherGrid = (n + 3) / 4;
    const int chunk1 = (e1 + BUCKET_BLOCKS - 1) / BUCKET_BLOCKS;
    const int chunk2 = (e2 + BUCKET_BLOCKS - 1) / BUCKET_BLOCKS;

    // ---- layer 1 ----
    init_cnt_kernel<<<(nb + 255) / 256, 256, 0, stream>>>(cnt, cap, nb);
    bucket_kernel<<<BUCKET_BLOCKS, 256, 0, stream>>>(ei1, pairs, cnt, flag, e1, cap, nb, chunk1);
    csr_local_kernel<<<nb, 256, 0, stream>>>(pairs, cnt, rps, rpe, esrc, cap, n);
    gather_mean128_kernel<<<gatherGrid, 256, 0, stream>>>((const uint4*)xb, rps, rpe,
                                                          esrc, (uint4*)agg, n);
    gemm1_kernel<<<640, 256, 0, stream>>>(agg, xb, W1l, W1r, b1, hb, n);

    // ---- layer 2 ----
    init_cnt_kernel<<<(nb + 255) / 256, 256, 0, stream>>>(cnt, cap, nb);
    bucket_kernel<<<BUCKET_BLOCKS, 256, 0, stream>>>(ei2, pairs, cnt, flag, e2, cap, nb, chunk2);
    csr_local_kernel<<<nb, 256, 0, stream>>>(pairs, cnt, rps, rpe, esrc, cap, n);
    gemmy2_kernel<<<512, 256, 0, stream>>>(hb, W2l, y2, n);
    gather_mean64_kernel<<<gatherGrid, 256, 0, stream>>>((const uint4*)y2, rps, rpe,
                                                         esrc, (uint4*)aggy, n);
    gemm2b_kernel<<<512, 256, 0, stream>>>(hb, aggy, W2r, b2, out, n);
}